// Round 1
// baseline (451.800 us; speedup 1.0000x reference)
//
#include <hip/hip_runtime.h>
#include <hip/hip_bf16.h>

// ---------------------------------------------------------------------------
// Gemma sliding-window attention layer, MI355X round 1 (correctness-first).
// Pipeline: cvt(f32->bf16) -> fused QKV GEMM (bf16 MFMA, f32 out) ->
//           RMSNorm+RoPE (f32) -> V transpose -> flash attn (SW=1024) ->
//           output GEMM.
// ---------------------------------------------------------------------------

typedef __bf16 bf16x8 __attribute__((ext_vector_type(8)));
typedef __bf16 bf16x4 __attribute__((ext_vector_type(4)));
typedef float f32x4 __attribute__((ext_vector_type(4)));

#define NB 2
#define SEQ 2048
#define DMODEL 2048
#define NH 8
#define NKV 4
#define DHEAD 256
#define SWIN 1024

#define AS1 __attribute__((address_space(1)))
#define AS3 __attribute__((address_space(3)))

static __device__ __forceinline__ void gload_lds16(const void* g, void* l) {
    __builtin_amdgcn_global_load_lds((const AS1 void*)g, (AS3 void*)l, 16, 0, 0);
}

// ------------------------- f32 -> bf16 convert ------------------------------
__global__ void cvt_f32_bf16(const float* __restrict__ in, __bf16* __restrict__ out, int n4) {
    int i = blockIdx.x * 256 + threadIdx.x;
    if (i >= n4) return;
    f32x4 v = ((const f32x4*)in)[i];
    bf16x4 o;
#pragma unroll
    for (int j = 0; j < 4; ++j) o[j] = (__bf16)v[j];
    ((bf16x4*)out)[i] = o;
}

// ------------------------- GEMM: C[M,N] = A[M,K] * B[N,K]^T ----------------
// A,B bf16 row-major (K contiguous). C f32. Tile 128x128, BK=32, 4 waves.
__global__ __launch_bounds__(256)
void gemm_bt(const __bf16* __restrict__ A, const __bf16* __restrict__ B,
             float* __restrict__ C, int M, int N, int K) {
    __shared__ __bf16 lA[128 * 32];
    __shared__ __bf16 lB[128 * 32];
    const int tid = threadIdx.x;
    const int wave = tid >> 6, lane = tid & 63;
    const int lo = lane & 15, hi = lane >> 4;
    const int brow = blockIdx.y * 128, bcol = blockIdx.x * 128;
    const int wr = (wave >> 1) * 64, wc = (wave & 1) * 64;
    f32x4 acc[4][4] = {};
    const int srow = tid >> 2, scol = (tid & 3) * 8;
    const __bf16* gA = A + (size_t)(brow + srow) * K + scol;
    const __bf16* gB = B + (size_t)(bcol + srow) * K + scol;
    char* la0 = (char*)lA + wave * 1024;
    char* la1 = (char*)lA + 4096 + wave * 1024;
    char* lb0 = (char*)lB + wave * 1024;
    char* lb1 = (char*)lB + 4096 + wave * 1024;
    const size_t rstep = (size_t)64 * K;
    for (int k0 = 0; k0 < K; k0 += 32) {
        gload_lds16(gA, la0);
        gload_lds16(gA + rstep, la1);
        gload_lds16(gB, lb0);
        gload_lds16(gB + rstep, lb1);
        __syncthreads();   // drains vmcnt -> LDS writes landed
        bf16x8 af[4], bfr[4];
#pragma unroll
        for (int m = 0; m < 4; ++m)
            af[m] = *(const bf16x8*)&lA[(wr + m * 16 + lo) * 32 + hi * 8];
#pragma unroll
        for (int n = 0; n < 4; ++n)
            bfr[n] = *(const bf16x8*)&lB[(wc + n * 16 + lo) * 32 + hi * 8];
#pragma unroll
        for (int m = 0; m < 4; ++m)
#pragma unroll
            for (int n = 0; n < 4; ++n)
                acc[m][n] = __builtin_amdgcn_mfma_f32_16x16x32_bf16(af[m], bfr[n], acc[m][n], 0, 0, 0);
        __syncthreads();
        gA += 32; gB += 32;
    }
#pragma unroll
    for (int m = 0; m < 4; ++m) {
        int row = brow + wr + m * 16 + hi * 4;
#pragma unroll
        for (int n = 0; n < 4; ++n) {
            float* cp = C + (size_t)row * N + bcol + wc + n * 16 + lo;
#pragma unroll
            for (int j = 0; j < 4; ++j)
                cp[(size_t)j * N] = acc[m][n][j];
        }
    }
}

// ------------------ RMSNorm + RoPE on q/k, write bf16 ----------------------
// grid = B*S blocks, 256 threads (4 waves); wave handles 3 of 12 normed heads.
__global__ __launch_bounds__(256)
void norm_rope(const float* __restrict__ QKV, const float* __restrict__ qw,
               const float* __restrict__ kw, __bf16* __restrict__ Qo,
               __bf16* __restrict__ Ko) {
    const int r = blockIdx.x;            // b*S + s
    const int b = r >> 11, s = r & (SEQ - 1);
    const int wave = threadIdx.x >> 6, lane = threadIdx.x & 63;
#pragma unroll
    for (int ii = 0; ii < 3; ++ii) {
        int hh = wave + ii * 4;          // 0..11 : 0-7 q heads, 8-11 k heads
        bool isq = hh < 8;
        int col0 = isq ? hh * DHEAD : DMODEL + (hh - 8) * DHEAD;
        const float* src = QKV + (size_t)r * 4096 + col0;
        float x[4];
        float ss = 0.f;
#pragma unroll
        for (int j = 0; j < 4; ++j) { x[j] = src[lane * 4 + j]; ss += x[j] * x[j]; }
#pragma unroll
        for (int d2 = 1; d2 < 64; d2 <<= 1) ss += __shfl_xor(ss, d2);
        float scale = rsqrtf(ss * (1.f / DHEAD) + 1e-6f);
        const float* wp = isq ? qw : kw;
        float nx[4];
#pragma unroll
        for (int j = 0; j < 4; ++j) {
            int d = lane * 4 + j;
            nx[j] = x[j] * scale * (1.f + wp[d]);
        }
        float outv[4];
#pragma unroll
        for (int j = 0; j < 4; ++j) {
            float other = __shfl_xor(nx[j], 32);
            int d = lane * 4 + j, i = d & 127;
            float fr = (float)s * __expf(-(float)i * 0.0719557843f);  // ln(1e4)/128
            float rot = (lane < 32) ? -other : other;
            outv[j] = nx[j] * cosf(fr) + rot * sinf(fr);
            if (isq) outv[j] *= 0.0625f;   // SCALE folded into q
        }
        __bf16* dst = isq ? (Qo + ((size_t)(b * NH + hh) * SEQ + s) * DHEAD)
                          : (Ko + ((size_t)(b * NKV + (hh - 8)) * SEQ + s) * DHEAD);
#pragma unroll
        for (int j = 0; j < 4; ++j) dst[lane * 4 + j] = (__bf16)outv[j];
    }
}

// ------------------ V: QKV f32 [.,3072+kh*256+d] -> VT bf16 [B,KVH,DH,S] ---
__global__ __launch_bounds__(256)
void vtrans(const float* __restrict__ QKV, __bf16* __restrict__ VT) {
    const int bk = blockIdx.z;                 // b*KVH + kh
    const int b = bk >> 2, kh = bk & 3;
    const int s0 = blockIdx.x * 64, d0 = blockIdx.y * 64;
    __shared__ float tile[64][65];
    const int t = threadIdx.x;
    const int col = t & 63, rbase = (t >> 6) * 16;
    const float* src = QKV + ((size_t)(b * SEQ + s0)) * 4096 + 3072 + kh * DHEAD + d0;
#pragma unroll
    for (int i = 0; i < 16; ++i)
        tile[rbase + i][col] = src[(size_t)(rbase + i) * 4096 + col];
    __syncthreads();
    __bf16* dst = VT + ((size_t)(b * NKV + kh) * DHEAD + d0) * SEQ + s0;
#pragma unroll
    for (int i = 0; i < 16; ++i)
        dst[(size_t)(rbase + i) * SEQ + col] = (__bf16)tile[col][rbase + i];
}

// ------------------ flash attention, sliding window ------------------------
// 1 wave per (b, h, 16 q rows). KV tiles of 32. Q hoisted in regs.
__global__ __launch_bounds__(64)
void attn(const __bf16* __restrict__ Q, const __bf16* __restrict__ Kb,
          const __bf16* __restrict__ VT, __bf16* __restrict__ ctx) {
    const int qt = blockIdx.x;
    const int bh = blockIdx.y;
    const int b = bh >> 3, h = bh & 7, kh = h >> 1;
    const int q0 = qt * 16;
    const int lane = threadIdx.x;
    const int lo = lane & 15, hi = lane >> 4;
    __shared__ __bf16 pl[16 * 32];
    const __bf16* Qp = Q + ((size_t)(b * NH + h) * SEQ + q0) * DHEAD;
    const __bf16* Kp = Kb + (size_t)(b * NKV + kh) * SEQ * DHEAD;
    const __bf16* Vp = VT + (size_t)(b * NKV + kh) * DHEAD * SEQ;
    bf16x8 qf[8];
#pragma unroll
    for (int c = 0; c < 8; ++c)
        qf[c] = *(const bf16x8*)(Qp + lo * DHEAD + c * 32 + hi * 8);
    f32x4 o[16] = {};
    float mj[4] = {-3e38f, -3e38f, -3e38f, -3e38f};
    float lj[4] = {0.f, 0.f, 0.f, 0.f};
    int kstart = q0 - (SWIN - 16);
    if (kstart < 0) kstart = 0;
    kstart &= ~31;
    for (int c0 = kstart; c0 <= q0 + 15; c0 += 32) {
        f32x4 sc0 = {}, sc1 = {};
#pragma unroll
        for (int c = 0; c < 8; ++c) {
            bf16x8 kf0 = *(const bf16x8*)(Kp + (size_t)(c0 + lo) * DHEAD + c * 32 + hi * 8);
            bf16x8 kf1 = *(const bf16x8*)(Kp + (size_t)(c0 + 16 + lo) * DHEAD + c * 32 + hi * 8);
            sc0 = __builtin_amdgcn_mfma_f32_16x16x32_bf16(qf[c], kf0, sc0, 0, 0, 0);
            sc1 = __builtin_amdgcn_mfma_f32_16x16x32_bf16(qf[c], kf1, sc1, 0, 0, 0);
        }
        __syncthreads();   // WAR: previous PV reads of pl done
#pragma unroll
        for (int j = 0; j < 4; ++j) {
            int r = q0 + hi * 4 + j;
            int ca = c0 + lo, cb = ca + 16;
            float sa = (ca <= r && r - ca < SWIN) ? sc0[j] : -1e30f;
            float sb = (cb <= r && r - cb < SWIN) ? sc1[j] : -1e30f;
            float pm = fmaxf(sa, sb);
#pragma unroll
            for (int d2 = 1; d2 < 16; d2 <<= 1) pm = fmaxf(pm, __shfl_xor(pm, d2));
            float mnew = fmaxf(mj[j], pm);
            float corr = __expf(mj[j] - mnew);
            float pa = __expf(sa - mnew);
            float pb = __expf(sb - mnew);
            float ps = pa + pb;
#pragma unroll
            for (int d2 = 1; d2 < 16; d2 <<= 1) ps += __shfl_xor(ps, d2);
            lj[j] = lj[j] * corr + ps;
            mj[j] = mnew;
#pragma unroll
            for (int dt = 0; dt < 16; ++dt) o[dt][j] *= corr;
            pl[(hi * 4 + j) * 32 + lo] = (__bf16)pa;
            pl[(hi * 4 + j) * 32 + 16 + lo] = (__bf16)pb;
        }
        __syncthreads();   // pl writes visible before re-fragment read
        bf16x8 paf = *(const bf16x8*)&pl[lo * 32 + hi * 8];
#pragma unroll
        for (int dt = 0; dt < 16; ++dt) {
            bf16x8 vf = *(const bf16x8*)(Vp + (size_t)(dt * 16 + lo) * SEQ + c0 + hi * 8);
            o[dt] = __builtin_amdgcn_mfma_f32_16x16x32_bf16(paf, vf, o[dt], 0, 0, 0);
        }
    }
    float invl[4];
#pragma unroll
    for (int j = 0; j < 4; ++j) invl[j] = 1.0f / lj[j];
    __bf16* cp = ctx + ((size_t)(b * SEQ) + q0) * (NH * DHEAD) + h * DHEAD;
#pragma unroll
    for (int dt = 0; dt < 16; ++dt)
#pragma unroll
        for (int j = 0; j < 4; ++j)
            cp[(size_t)(hi * 4 + j) * (NH * DHEAD) + dt * 16 + lo] = (__bf16)(o[dt][j] * invl[j]);
}

// ---------------------------------------------------------------------------
extern "C" void kernel_launch(void* const* d_in, const int* in_sizes, int n_in,
                              void* d_out, int out_size, void* d_ws, size_t ws_size,
                              hipStream_t stream) {
    const float* hs = (const float*)d_in[0];
    const float* Wq = (const float*)d_in[1];
    const float* Wk = (const float*)d_in[2];
    const float* Wv = (const float*)d_in[3];
    const float* Wo = (const float*)d_in[4];
    const float* qw = (const float*)d_in[5];
    const float* kw = (const float*)d_in[6];
    float* out = (float*)d_out;

    char* ws = (char*)d_ws;
    size_t off = 0;
    auto alloc = [&](size_t bytes) {
        char* p = ws + off;
        off += (bytes + 255) & ~(size_t)255;
        return p;
    };
    const int M = NB * SEQ;                       // 4096
    __bf16* hsB   = (__bf16*)alloc((size_t)M * DMODEL * 2);
    __bf16* WqkvB = (__bf16*)alloc((size_t)4096 * DMODEL * 2);
    __bf16* WoB   = (__bf16*)alloc((size_t)DMODEL * DMODEL * 2);
    float*  QKV   = (float*) alloc((size_t)M * 4096 * 4);
    __bf16* Qb    = (__bf16*)alloc((size_t)M * NH * DHEAD / 1 * 2 / 2 * 2);   // M*2048 bf16
    __bf16* Kbf   = (__bf16*)alloc((size_t)M * 1024 * 2);
    __bf16* VTb   = (__bf16*)alloc((size_t)M * 1024 * 2);
    __bf16* ctxB  = (__bf16*)QKV;                 // reuse: QKV dead after vtrans

    // converts
    cvt_f32_bf16<<<8192, 256, 0, stream>>>(hs, hsB, M * DMODEL / 4);
    cvt_f32_bf16<<<4096, 256, 0, stream>>>(Wq, WqkvB, 2048 * 2048 / 4);
    cvt_f32_bf16<<<2048, 256, 0, stream>>>(Wk, WqkvB + (size_t)2048 * 2048, 1024 * 2048 / 4);
    cvt_f32_bf16<<<2048, 256, 0, stream>>>(Wv, WqkvB + (size_t)3072 * 2048, 1024 * 2048 / 4);
    cvt_f32_bf16<<<4096, 256, 0, stream>>>(Wo, WoB, 2048 * 2048 / 4);

    // fused QKV projection
    gemm_bt<<<dim3(32, 32), 256, 0, stream>>>(hsB, WqkvB, QKV, M, 4096, DMODEL);

    // norm + rope; V transpose
    norm_rope<<<M, 256, 0, stream>>>(QKV, qw, kw, Qb, Kbf);
    vtrans<<<dim3(SEQ / 64, DHEAD / 64, NB * NKV), 256, 0, stream>>>(QKV, VTb);

    // attention
    attn<<<dim3(SEQ / 16, NB * NH), 64, 0, stream>>>(Qb, Kbf, VTb, ctxB);

    // output projection
    gemm_bt<<<dim3(16, 32), 256, 0, stream>>>(ctxB, WoB, out, M, DMODEL, DMODEL);
}

// Round 2
// 353.115 us; speedup vs baseline: 1.2795x; 1.2795x over previous
//
#include <hip/hip_runtime.h>
#include <hip/hip_bf16.h>

// ---------------------------------------------------------------------------
// Gemma sliding-window attention layer, MI355X round 2.
// attn rewritten: 4-wave blocks, LDS-staged swizzled K, swapped QK^T and
// swapped PV (lane-parallel softmax, q-keyed state), defer-max, XCD grouping.
// ---------------------------------------------------------------------------

typedef __bf16 bf16x8 __attribute__((ext_vector_type(8)));
typedef __bf16 bf16x4 __attribute__((ext_vector_type(4)));
typedef float f32x4 __attribute__((ext_vector_type(4)));

#define NB 2
#define SEQ 2048
#define DMODEL 2048
#define NH 8
#define NKV 4
#define DHEAD 256
#define SWIN 1024

#define AS1 __attribute__((address_space(1)))
#define AS3 __attribute__((address_space(3)))

static __device__ __forceinline__ void gload_lds16(const void* g, void* l) {
    __builtin_amdgcn_global_load_lds((const AS1 void*)g, (AS3 void*)l, 16, 0, 0);
}

// ------------------------- f32 -> bf16 convert ------------------------------
__global__ void cvt_f32_bf16(const float* __restrict__ in, __bf16* __restrict__ out, int n4) {
    int i = blockIdx.x * 256 + threadIdx.x;
    if (i >= n4) return;
    f32x4 v = ((const f32x4*)in)[i];
    bf16x4 o;
#pragma unroll
    for (int j = 0; j < 4; ++j) o[j] = (__bf16)v[j];
    ((bf16x4*)out)[i] = o;
}

// ------------------------- GEMM: C[M,N] = A[M,K] * B[N,K]^T ----------------
__global__ __launch_bounds__(256)
void gemm_bt(const __bf16* __restrict__ A, const __bf16* __restrict__ B,
             float* __restrict__ C, int M, int N, int K) {
    __shared__ __bf16 lA[128 * 32];
    __shared__ __bf16 lB[128 * 32];
    const int tid = threadIdx.x;
    const int wave = tid >> 6, lane = tid & 63;
    const int lo = lane & 15, hi = lane >> 4;
    const int brow = blockIdx.y * 128, bcol = blockIdx.x * 128;
    const int wr = (wave >> 1) * 64, wc = (wave & 1) * 64;
    f32x4 acc[4][4] = {};
    const int srow = tid >> 2, scol = (tid & 3) * 8;
    const __bf16* gA = A + (size_t)(brow + srow) * K + scol;
    const __bf16* gB = B + (size_t)(bcol + srow) * K + scol;
    char* la0 = (char*)lA + wave * 1024;
    char* la1 = (char*)lA + 4096 + wave * 1024;
    char* lb0 = (char*)lB + wave * 1024;
    char* lb1 = (char*)lB + 4096 + wave * 1024;
    const size_t rstep = (size_t)64 * K;
    for (int k0 = 0; k0 < K; k0 += 32) {
        gload_lds16(gA, la0);
        gload_lds16(gA + rstep, la1);
        gload_lds16(gB, lb0);
        gload_lds16(gB + rstep, lb1);
        __syncthreads();
        bf16x8 af[4], bfr[4];
#pragma unroll
        for (int m = 0; m < 4; ++m)
            af[m] = *(const bf16x8*)&lA[(wr + m * 16 + lo) * 32 + hi * 8];
#pragma unroll
        for (int n = 0; n < 4; ++n)
            bfr[n] = *(const bf16x8*)&lB[(wc + n * 16 + lo) * 32 + hi * 8];
#pragma unroll
        for (int m = 0; m < 4; ++m)
#pragma unroll
            for (int n = 0; n < 4; ++n)
                acc[m][n] = __builtin_amdgcn_mfma_f32_16x16x32_bf16(af[m], bfr[n], acc[m][n], 0, 0, 0);
        __syncthreads();
        gA += 32; gB += 32;
    }
#pragma unroll
    for (int m = 0; m < 4; ++m) {
        int row = brow + wr + m * 16 + hi * 4;
#pragma unroll
        for (int n = 0; n < 4; ++n) {
            float* cp = C + (size_t)row * N + bcol + wc + n * 16 + lo;
#pragma unroll
            for (int j = 0; j < 4; ++j)
                cp[(size_t)j * N] = acc[m][n][j];
        }
    }
}

// ------------------ RMSNorm + RoPE on q/k, write bf16 ----------------------
__global__ __launch_bounds__(256)
void norm_rope(const float* __restrict__ QKV, const float* __restrict__ qw,
               const float* __restrict__ kw, __bf16* __restrict__ Qo,
               __bf16* __restrict__ Ko) {
    const int r = blockIdx.x;            // b*S + s
    const int b = r >> 11, s = r & (SEQ - 1);
    const int wave = threadIdx.x >> 6, lane = threadIdx.x & 63;
#pragma unroll
    for (int ii = 0; ii < 3; ++ii) {
        int hh = wave + ii * 4;          // 0..11 : 0-7 q heads, 8-11 k heads
        bool isq = hh < 8;
        int col0 = isq ? hh * DHEAD : DMODEL + (hh - 8) * DHEAD;
        const float* src = QKV + (size_t)r * 4096 + col0;
        float x[4];
        float ss = 0.f;
#pragma unroll
        for (int j = 0; j < 4; ++j) { x[j] = src[lane * 4 + j]; ss += x[j] * x[j]; }
#pragma unroll
        for (int d2 = 1; d2 < 64; d2 <<= 1) ss += __shfl_xor(ss, d2);
        float scale = rsqrtf(ss * (1.f / DHEAD) + 1e-6f);
        const float* wp = isq ? qw : kw;
        float nx[4];
#pragma unroll
        for (int j = 0; j < 4; ++j) {
            int d = lane * 4 + j;
            nx[j] = x[j] * scale * (1.f + wp[d]);
        }
        float outv[4];
#pragma unroll
        for (int j = 0; j < 4; ++j) {
            float other = __shfl_xor(nx[j], 32);
            int d = lane * 4 + j, i = d & 127;
            float fr = (float)s * __expf(-(float)i * 0.0719557843f);  // ln(1e4)/128
            float rot = (lane < 32) ? -other : other;
            outv[j] = nx[j] * cosf(fr) + rot * sinf(fr);
            if (isq) outv[j] *= 0.0625f;   // SCALE folded into q
        }
        __bf16* dst = isq ? (Qo + ((size_t)(b * NH + hh) * SEQ + s) * DHEAD)
                          : (Ko + ((size_t)(b * NKV + (hh - 8)) * SEQ + s) * DHEAD);
#pragma unroll
        for (int j = 0; j < 4; ++j) dst[lane * 4 + j] = (__bf16)outv[j];
    }
}

// ------------------ V: QKV f32 -> VT bf16 [B,KVH,DH,S] ---------------------
__global__ __launch_bounds__(256)
void vtrans(const float* __restrict__ QKV, __bf16* __restrict__ VT) {
    const int bk = blockIdx.z;                 // b*KVH + kh
    const int b = bk >> 2, kh = bk & 3;
    const int s0 = blockIdx.x * 64, d0 = blockIdx.y * 64;
    __shared__ float tile[64][65];
    const int t = threadIdx.x;
    const int col = t & 63, rbase = (t >> 6) * 16;
    const float* src = QKV + ((size_t)(b * SEQ + s0)) * 4096 + 3072 + kh * DHEAD + d0;
#pragma unroll
    for (int i = 0; i < 16; ++i)
        tile[rbase + i][col] = src[(size_t)(rbase + i) * 4096 + col];
    __syncthreads();
    __bf16* dst = VT + ((size_t)(b * NKV + kh) * DHEAD + d0) * SEQ + s0;
#pragma unroll
    for (int i = 0; i < 16; ++i)
        dst[(size_t)(rbase + i) * SEQ + col] = (__bf16)tile[col][rbase + i];
}

// ------------------ flash attention v2 -------------------------------------
// Block: (b,kh) x 32 q-rows; 4 waves = 2 heads x 2 q-subtiles of 16 rows.
// K tile (32x256 bf16) staged in LDS, XOR-swizzled (16B units: u ^= row&7).
// Swapped QK^T: C[key][q] -> lane-parallel softmax keyed q = lane&15.
// Swapped PV:   O^T[d][q] -> rescale keyed q, no cross-lane redistribution.
__global__ __launch_bounds__(256)
void attn2(const __bf16* __restrict__ Q, const __bf16* __restrict__ Kb,
           const __bf16* __restrict__ VT, __bf16* __restrict__ ctx) {
    const int bid = blockIdx.x;
    const int bk = bid & 7;            // XCD grouping: same (b,kh) -> same XCD
    const int qt = bid >> 3;
    const int b = bk >> 2, kh = bk & 3;
    const int q0 = qt * 32;
    const int tid = threadIdx.x;
    const int wave = tid >> 6, lane = tid & 63;
    const int lo = lane & 15, hi = lane >> 4;
    const int hsel = wave >> 1, qsub = wave & 1;
    const int h = kh * 2 + hsel;
    const int qbase = q0 + qsub * 16;
    const int q = qbase + lo;

    __shared__ __bf16 kbuf[2][32 * 256];      // 32 KB, dbuf
    __shared__ __bf16 plb[4][2][16 * 40];     // per-wave P^T routing, padded

    const __bf16* Qp = Q + ((size_t)(b * NH + h) * SEQ + qbase) * DHEAD;
    const __bf16* Kp = Kb + (size_t)(b * NKV + kh) * SEQ * DHEAD;
    const __bf16* Vp = VT + (size_t)(b * NKV + kh) * DHEAD * SEQ;

    bf16x8 qf[8];
#pragma unroll
    for (int dc = 0; dc < 8; ++dc)
        qf[dc] = *(const bf16x8*)(Qp + (size_t)lo * DHEAD + dc * 32 + hi * 8);

    f32x4 o[16] = {};
    float m = -3e38f, l = 0.f;

    int kstart = q0 - SWIN; if (kstart < 0) kstart = 0;
    const int nt = (q0 + 32 - kstart) >> 5;

    // stage K tile t into kbuf[buf]: LDS[r][c] = G[r][c ^ (r&7)]  (16B units)
    auto stage = [&](int bsel, int c0) {
#pragma unroll
        for (int i = 0; i < 4; ++i) {
            int n = i * 256 + tid;             // 16B slot
            int r = n >> 5, c = n & 31;
            const __bf16* g = Kp + (size_t)(c0 + r) * DHEAD + (c ^ (r & 7)) * 8;
            gload_lds16(g, (char*)&kbuf[bsel][0] + (i * 256 + wave * 64) * 16);
        }
    };

    stage(0, kstart);
    __syncthreads();
    int buf = 0;
    for (int t = 0; t < nt; ++t) {
        const int c0 = kstart + t * 32;
        if (t + 1 < nt) stage(buf ^ 1, c0 + 32);

        // ---- QK^T (swapped): sc0 keys c0+hi*4+j, sc1 keys c0+16+hi*4+j, q=lo
        f32x4 sc0 = {}, sc1 = {};
        const __bf16* kb0 = &kbuf[buf][0];
#pragma unroll
        for (int dc = 0; dc < 8; ++dc) {
            int u = dc * 4 + hi;
            bf16x8 kfa = *(const bf16x8*)&kb0[lo * 256 + (u ^ (lo & 7)) * 8];
            bf16x8 kfb = *(const bf16x8*)&kb0[(16 + lo) * 256 + (u ^ (lo & 7)) * 8];
            sc0 = __builtin_amdgcn_mfma_f32_16x16x32_bf16(kfa, qf[dc], sc0, 0, 0, 0);
            sc1 = __builtin_amdgcn_mfma_f32_16x16x32_bf16(kfb, qf[dc], sc1, 0, 0, 0);
        }

        // ---- mask + lane-parallel online softmax (state keyed q = lo)
        float s8[8];
#pragma unroll
        for (int j = 0; j < 4; ++j) {
            int ka = c0 + hi * 4 + j;
            int kb2 = ka + 16;
            s8[j]     = (ka <= q && q - ka < SWIN) ? sc0[j] : -1e30f;
            s8[4 + j] = (kb2 <= q && q - kb2 < SWIN) ? sc1[j] : -1e30f;
        }
        float pm = s8[0];
#pragma unroll
        for (int i = 1; i < 8; ++i) pm = fmaxf(pm, s8[i]);
        pm = fmaxf(pm, __shfl_xor(pm, 16));
        pm = fmaxf(pm, __shfl_xor(pm, 32));
        if (__any(pm > m + 8.f)) {             // T13 defer-max
            float mn = fmaxf(m, pm);
            float corr = __expf(m - mn);
            l *= corr;
#pragma unroll
            for (int dt = 0; dt < 16; ++dt) o[dt] *= corr;
            m = mn;
        }
        float p8[8], ps = 0.f;
#pragma unroll
        for (int i = 0; i < 8; ++i) {
            float e = __expf(s8[i] - m);
            p8[i] = (s8[i] > -9e29f) ? e : 0.f;
            ps += p8[i];
        }
        ps += __shfl_xor(ps, 16);
        ps += __shfl_xor(ps, 32);
        l += ps;

        // ---- route P^T through per-wave LDS (no barrier: wave-internal)
        __bf16* pw = &plb[wave][t & 1][0];
        bf16x4 pa, pb;
#pragma unroll
        for (int j = 0; j < 4; ++j) { pa[j] = (__bf16)p8[j]; pb[j] = (__bf16)p8[4 + j]; }
        *(bf16x4*)&pw[lo * 40 + hi * 4] = pa;
        *(bf16x4*)&pw[lo * 40 + 16 + hi * 4] = pb;
        bf16x8 paf = *(const bf16x8*)&pw[lo * 40 + hi * 8];   // B-frag P^T[k][q]

        // ---- PV (swapped): o[dt][j] = O[d = dt*16+hi*4+j][q = lo]
#pragma unroll
        for (int dt = 0; dt < 16; ++dt) {
            bf16x8 vf = *(const bf16x8*)(Vp + (size_t)(dt * 16 + lo) * SEQ + c0 + hi * 8);
            o[dt] = __builtin_amdgcn_mfma_f32_16x16x32_bf16(vf, paf, o[dt], 0, 0, 0);
        }
        __syncthreads();
        buf ^= 1;
    }

    const float invl = 1.0f / l;
    __bf16* cp = ctx + ((size_t)(b * SEQ + q)) * (NH * DHEAD) + h * DHEAD;
#pragma unroll
    for (int dt = 0; dt < 16; ++dt) {
        bf16x4 w;
#pragma unroll
        for (int j = 0; j < 4; ++j) w[j] = (__bf16)(o[dt][j] * invl);
        *(bf16x4*)&cp[dt * 16 + hi * 4] = w;
    }
}

// ---------------------------------------------------------------------------
extern "C" void kernel_launch(void* const* d_in, const int* in_sizes, int n_in,
                              void* d_out, int out_size, void* d_ws, size_t ws_size,
                              hipStream_t stream) {
    const float* hs = (const float*)d_in[0];
    const float* Wq = (const float*)d_in[1];
    const float* Wk = (const float*)d_in[2];
    const float* Wv = (const float*)d_in[3];
    const float* Wo = (const float*)d_in[4];
    const float* qw = (const float*)d_in[5];
    const float* kw = (const float*)d_in[6];
    float* out = (float*)d_out;

    char* ws = (char*)d_ws;
    size_t off = 0;
    auto alloc = [&](size_t bytes) {
        char* p = ws + off;
        off += (bytes + 255) & ~(size_t)255;
        return p;
    };
    const int M = NB * SEQ;                       // 4096
    __bf16* hsB   = (__bf16*)alloc((size_t)M * DMODEL * 2);
    __bf16* WqkvB = (__bf16*)alloc((size_t)4096 * DMODEL * 2);
    __bf16* WoB   = (__bf16*)alloc((size_t)DMODEL * DMODEL * 2);
    float*  QKV   = (float*) alloc((size_t)M * 4096 * 4);
    __bf16* Qb    = (__bf16*)alloc((size_t)M * 2048 * 2);
    __bf16* Kbf   = (__bf16*)alloc((size_t)M * 1024 * 2);
    __bf16* VTb   = (__bf16*)alloc((size_t)M * 1024 * 2);
    __bf16* ctxB  = (__bf16*)QKV;                 // reuse: QKV dead after vtrans

    cvt_f32_bf16<<<8192, 256, 0, stream>>>(hs, hsB, M * DMODEL / 4);
    cvt_f32_bf16<<<4096, 256, 0, stream>>>(Wq, WqkvB, 2048 * 2048 / 4);
    cvt_f32_bf16<<<2048, 256, 0, stream>>>(Wk, WqkvB + (size_t)2048 * 2048, 1024 * 2048 / 4);
    cvt_f32_bf16<<<2048, 256, 0, stream>>>(Wv, WqkvB + (size_t)3072 * 2048, 1024 * 2048 / 4);
    cvt_f32_bf16<<<4096, 256, 0, stream>>>(Wo, WoB, 2048 * 2048 / 4);

    gemm_bt<<<dim3(32, 32), 256, 0, stream>>>(hsB, WqkvB, QKV, M, 4096, DMODEL);

    norm_rope<<<M, 256, 0, stream>>>(QKV, qw, kw, Qb, Kbf);
    vtrans<<<dim3(SEQ / 64, DHEAD / 64, NB * NKV), 256, 0, stream>>>(QKV, VTb);

    attn2<<<512, 256, 0, stream>>>(Qb, Kbf, VTb, ctxB);

    gemm_bt<<<dim3(16, 32), 256, 0, stream>>>(ctxB, WoB, out, M, DMODEL, DMODEL);
}

// Round 3
// 286.263 us; speedup vs baseline: 1.5783x; 1.2335x over previous
//
#include <hip/hip_runtime.h>
#include <hip/hip_bf16.h>

// ---------------------------------------------------------------------------
// Gemma sliding-window attention layer, MI355X round 3.
// attn: K+V both LDS-staged (V subtiled for ds_read_b64_tr_b16), swapped
// QK^T + swapped PV with consistent k-permutation -> P stays in registers.
// vtrans kernel eliminated (V convert fused into norm_rope, row-major V).
// RoPE via precomputed cos/sin tables.
// ---------------------------------------------------------------------------

typedef __bf16 bf16x8 __attribute__((ext_vector_type(8)));
typedef __bf16 bf16x4 __attribute__((ext_vector_type(4)));
typedef float f32x4 __attribute__((ext_vector_type(4)));

#define NB 2
#define SEQ 2048
#define DMODEL 2048
#define NH 8
#define NKV 4
#define DHEAD 256
#define SWIN 1024

#define AS1 __attribute__((address_space(1)))
#define AS3 __attribute__((address_space(3)))

static __device__ __forceinline__ void gload_lds16(const void* g, void* l) {
    __builtin_amdgcn_global_load_lds((const AS1 void*)g, (AS3 void*)l, 16, 0, 0);
}

// hardware transpose read: 4 bf16 per lane, 16-lane group reads one [4][16]
// bf16 subtile (128 B); lane lo gets column lo, elem j = row j.
static __device__ __forceinline__ bf16x4 tr16(const __bf16* p) {
    bf16x4 r;
    asm volatile("ds_read_b64_tr_b16 %0, %1" : "=v"(r) : "v"((const AS3 __bf16*)p));
    return r;
}

// ------------------------- f32 -> bf16 convert ------------------------------
__global__ void cvt_f32_bf16(const float* __restrict__ in, __bf16* __restrict__ out, int n4) {
    int i = blockIdx.x * 256 + threadIdx.x;
    if (i >= n4) return;
    f32x4 v = ((const f32x4*)in)[i];
    bf16x4 o;
#pragma unroll
    for (int j = 0; j < 4; ++j) o[j] = (__bf16)v[j];
    ((bf16x4*)out)[i] = o;
}

// ------------------------- RoPE cos/sin table -------------------------------
__global__ void rope_tab(float* __restrict__ cosT, float* __restrict__ sinT) {
    int s = blockIdx.x, i = threadIdx.x;           // i in 0..127
    float fr = (float)s * __expf(-(float)i * 0.0719557843f);  // ln(1e4)/128
    cosT[s * 128 + i] = cosf(fr);
    sinT[s * 128 + i] = sinf(fr);
}

// ------------------------- GEMM: C[M,N] = A[M,K] * B[N,K]^T ----------------
__global__ __launch_bounds__(256)
void gemm_bt(const __bf16* __restrict__ A, const __bf16* __restrict__ B,
             float* __restrict__ C, int M, int N, int K) {
    __shared__ __bf16 lA[128 * 32];
    __shared__ __bf16 lB[128 * 32];
    const int tid = threadIdx.x;
    const int wave = tid >> 6, lane = tid & 63;
    const int lo = lane & 15, hi = lane >> 4;
    const int brow = blockIdx.y * 128, bcol = blockIdx.x * 128;
    const int wr = (wave >> 1) * 64, wc = (wave & 1) * 64;
    f32x4 acc[4][4] = {};
    const int srow = tid >> 2, scol = (tid & 3) * 8;
    const __bf16* gA = A + (size_t)(brow + srow) * K + scol;
    const __bf16* gB = B + (size_t)(bcol + srow) * K + scol;
    char* la0 = (char*)lA + wave * 1024;
    char* la1 = (char*)lA + 4096 + wave * 1024;
    char* lb0 = (char*)lB + wave * 1024;
    char* lb1 = (char*)lB + 4096 + wave * 1024;
    const size_t rstep = (size_t)64 * K;
    for (int k0 = 0; k0 < K; k0 += 32) {
        gload_lds16(gA, la0);
        gload_lds16(gA + rstep, la1);
        gload_lds16(gB, lb0);
        gload_lds16(gB + rstep, lb1);
        __syncthreads();
        bf16x8 af[4], bfr[4];
#pragma unroll
        for (int m = 0; m < 4; ++m)
            af[m] = *(const bf16x8*)&lA[(wr + m * 16 + lo) * 32 + hi * 8];
#pragma unroll
        for (int n = 0; n < 4; ++n)
            bfr[n] = *(const bf16x8*)&lB[(wc + n * 16 + lo) * 32 + hi * 8];
#pragma unroll
        for (int m = 0; m < 4; ++m)
#pragma unroll
            for (int n = 0; n < 4; ++n)
                acc[m][n] = __builtin_amdgcn_mfma_f32_16x16x32_bf16(af[m], bfr[n], acc[m][n], 0, 0, 0);
        __syncthreads();
        gA += 32; gB += 32;
    }
#pragma unroll
    for (int m = 0; m < 4; ++m) {
        int row = brow + wr + m * 16 + hi * 4;
#pragma unroll
        for (int n = 0; n < 4; ++n) {
            float* cp = C + (size_t)row * N + bcol + wc + n * 16 + lo;
#pragma unroll
            for (int j = 0; j < 4; ++j)
                cp[(size_t)j * N] = acc[m][n][j];
        }
    }
}

// ---------- RMSNorm + RoPE (q,k) + V convert, all from QKV f32 -------------
// grid = B*S blocks, 256 threads; wave handles 4 of 16 tasks
// (tasks 0-7: q heads, 8-11: k heads, 12-15: v heads = plain convert).
__global__ __launch_bounds__(256)
void norm_rope(const float* __restrict__ QKV, const float* __restrict__ qw,
               const float* __restrict__ kw, const float* __restrict__ cosT,
               const float* __restrict__ sinT, __bf16* __restrict__ Qo,
               __bf16* __restrict__ Ko, __bf16* __restrict__ Vo) {
    const int r = blockIdx.x;            // b*S + s
    const int b = r >> 11, s = r & (SEQ - 1);
    const int wave = threadIdx.x >> 6, lane = threadIdx.x & 63;
    f32x4 cos4 = *(const f32x4*)&cosT[s * 128 + (lane & 31) * 4];
    f32x4 sin4 = *(const f32x4*)&sinT[s * 128 + (lane & 31) * 4];
#pragma unroll
    for (int ii = 0; ii < 4; ++ii) {
        int hh = wave + ii * 4;          // 0..15
        if (hh < 12) {
            bool isq = hh < 8;
            int col0 = isq ? hh * DHEAD : DMODEL + (hh - 8) * DHEAD;
            const float* src = QKV + (size_t)r * 4096 + col0;
            f32x4 x = *(const f32x4*)&src[lane * 4];
            float ss = x[0] * x[0] + x[1] * x[1] + x[2] * x[2] + x[3] * x[3];
#pragma unroll
            for (int d2 = 1; d2 < 64; d2 <<= 1) ss += __shfl_xor(ss, d2);
            float scale = rsqrtf(ss * (1.f / DHEAD) + 1e-6f);
            const float* wp = isq ? qw : kw;
            float nx[4];
#pragma unroll
            for (int j = 0; j < 4; ++j)
                nx[j] = x[j] * scale * (1.f + wp[lane * 4 + j]);
            bf16x4 ov;
#pragma unroll
            for (int j = 0; j < 4; ++j) {
                float other = __shfl_xor(nx[j], 32);
                float rot = (lane < 32) ? -other : other;
                float v = nx[j] * cos4[j] + rot * sin4[j];
                if (isq) v *= 0.0625f;   // SCALE folded into q
                ov[j] = (__bf16)v;
            }
            __bf16* dst = isq ? (Qo + ((size_t)(b * NH + hh) * SEQ + s) * DHEAD)
                              : (Ko + ((size_t)(b * NKV + (hh - 8)) * SEQ + s) * DHEAD);
            *(bf16x4*)&dst[lane * 4] = ov;
        } else {
            int vh = hh - 12;
            const float* src = QKV + (size_t)r * 4096 + 3072 + vh * DHEAD;
            f32x4 x = *(const f32x4*)&src[lane * 4];
            bf16x4 ov;
#pragma unroll
            for (int j = 0; j < 4; ++j) ov[j] = (__bf16)x[j];
            __bf16* dst = Vo + ((size_t)(b * NKV + vh) * SEQ + s) * DHEAD;
            *(bf16x4*)&dst[lane * 4] = ov;
        }
    }
}

// ------------------ flash attention v3 -------------------------------------
// Block: (b,kh) x 32 q-rows; 4 waves = 2 heads x 2 q-subtiles of 16 rows.
// K tile [32][256] XOR-swizzled in LDS; V tile subtiled [d/16][k/4][4][16]
// for ds_read_b64_tr_b16. P never leaves registers (consistent k-perm on
// both PV operands). Double-buffered, 1 barrier per tile.
__global__ __launch_bounds__(256)
void attn3(const __bf16* __restrict__ Q, const __bf16* __restrict__ Kb,
           const __bf16* __restrict__ Vb, __bf16* __restrict__ ctx) {
    const int bid = blockIdx.x;
    const int bk = bid & 7;            // XCD grouping: same (b,kh) -> same XCD
    const int qt = bid >> 3;
    const int b = bk >> 2, kh = bk & 3;
    const int q0 = qt * 32;
    const int tid = threadIdx.x;
    const int wave = tid >> 6, lane = tid & 63;
    const int lo = lane & 15, hi = lane >> 4;
    const int hsel = wave >> 1, qsub = wave & 1;
    const int h = kh * 2 + hsel;
    const int qbase = q0 + qsub * 16;
    const int q = qbase + lo;

    __shared__ __align__(16) __bf16 kbuf[2][32 * 256];   // 2 x 16 KB
    __shared__ __align__(16) __bf16 vbuf[2][32 * 256];   // 2 x 16 KB

    const __bf16* Qp = Q + ((size_t)(b * NH + h) * SEQ + qbase) * DHEAD;
    const __bf16* Kp = Kb + (size_t)(b * NKV + kh) * SEQ * DHEAD;
    const __bf16* Vp = Vb + (size_t)(b * NKV + kh) * SEQ * DHEAD;

    // per-thread staging source offsets (elements), loop-invariant.
    // K: LDS[r][c16] = G[r][c16 ^ (r&7)]  (16B units within row)
    // V: LDS subtile layout elem((k,d)) = ((d>>4)*8 + (k>>2))*64 + (k&3)*16 + (d&15)
    int koff[4], voff[4];
#pragma unroll
    for (int i = 0; i < 4; ++i) {
        int n = i * 256 + tid;                 // 16B slot index
        int r = n >> 5, c = n & 31;
        koff[i] = r * 256 + ((c ^ (r & 7)) << 3);
        int st = n >> 3, w = n & 7;
        int vk = (st & 7) * 4 + (w >> 1);
        int vd = (st >> 3) * 16 + (w & 1) * 8;
        voff[i] = vk * 256 + vd;
    }

    auto stage = [&](int bsel, int c0) {
        const __bf16* kg = Kp + (size_t)c0 * DHEAD;
        const __bf16* vg = Vp + (size_t)c0 * DHEAD;
        char* kd = (char*)&kbuf[bsel][0] + wave * 1024;
        char* vd = (char*)&vbuf[bsel][0] + wave * 1024;
#pragma unroll
        for (int i = 0; i < 4; ++i) {
            gload_lds16(kg + koff[i], kd + i * 4096);
            gload_lds16(vg + voff[i], vd + i * 4096);
        }
    };

    bf16x8 qf[8];
#pragma unroll
    for (int dc = 0; dc < 8; ++dc)
        qf[dc] = *(const bf16x8*)(Qp + (size_t)lo * DHEAD + dc * 32 + hi * 8);

    f32x4 o[16] = {};
    float m = -3e38f, l = 0.f;

    int kstart = q0 - SWIN; if (kstart < 0) kstart = 0;
    const int nt = (q0 + 32 - kstart) >> 5;

    stage(0, kstart);
    __syncthreads();
    int buf = 0;
    for (int t = 0; t < nt; ++t) {
        const int c0 = kstart + t * 32;
        if (t + 1 < nt) stage(buf ^ 1, c0 + 32);

        // ---- QK^T (swapped): keys c0+hi*4+j (sc0) / +16 (sc1), q = lo
        f32x4 sc0 = {}, sc1 = {};
        const __bf16* kb0 = &kbuf[buf][0];
        __builtin_amdgcn_s_setprio(1);
#pragma unroll
        for (int dc = 0; dc < 8; ++dc) {
            int u = dc * 4 + hi;
            bf16x8 kfa = *(const bf16x8*)&kb0[lo * 256 + ((u ^ (lo & 7)) << 3)];
            bf16x8 kfb = *(const bf16x8*)&kb0[(16 + lo) * 256 + ((u ^ ((16 + lo) & 7)) << 3)];
            sc0 = __builtin_amdgcn_mfma_f32_16x16x32_bf16(kfa, qf[dc], sc0, 0, 0, 0);
            sc1 = __builtin_amdgcn_mfma_f32_16x16x32_bf16(kfb, qf[dc], sc1, 0, 0, 0);
        }
        __builtin_amdgcn_s_setprio(0);

        // ---- mask + lane-parallel online softmax (state keyed q = lo)
        float s8[8];
#pragma unroll
        for (int j = 0; j < 4; ++j) {
            int ka = c0 + hi * 4 + j;
            int kb2 = ka + 16;
            s8[j]     = (ka <= q && q - ka < SWIN) ? sc0[j] : -1e30f;
            s8[4 + j] = (kb2 <= q && q - kb2 < SWIN) ? sc1[j] : -1e30f;
        }
        float pm = s8[0];
#pragma unroll
        for (int i = 1; i < 8; ++i) pm = fmaxf(pm, s8[i]);
        pm = fmaxf(pm, __shfl_xor(pm, 16));
        pm = fmaxf(pm, __shfl_xor(pm, 32));
        if (__any(pm > m + 8.f)) {             // T13 defer-max
            float mn = fmaxf(m, pm);
            float corr = __expf(m - mn);
            l *= corr;
#pragma unroll
            for (int dt = 0; dt < 16; ++dt) o[dt] *= corr;
            m = mn;
        }
        float p8[8], ps = 0.f;
#pragma unroll
        for (int i = 0; i < 8; ++i) {
            float e = __expf(s8[i] - m);
            p8[i] = (s8[i] > -9e29f) ? e : 0.f;
            ps += p8[i];
        }
        ps += __shfl_xor(ps, 16);
        ps += __shfl_xor(ps, 32);
        l += ps;

        // B-operand for PV directly from registers: elem j<4 -> key hi*4+j,
        // elem j>=4 -> key 16+hi*4+(j-4); same permutation used on A (tr reads).
        bf16x8 paf;
#pragma unroll
        for (int i = 0; i < 8; ++i) paf[i] = (__bf16)p8[i];

        // ---- PV (swapped): o[dt][r] = O^T[d = dt*16+hi*4+r][q = lo]
        const __bf16* vb0 = &vbuf[buf][0];
#pragma unroll
        for (int dq = 0; dq < 4; ++dq) {
            bf16x4 t0[4], t1[4];
#pragma unroll
            for (int u = 0; u < 4; ++u) {
                int dt = dq * 4 + u;
                t0[u] = tr16(vb0 + (dt * 8 + hi) * 64 + lo * 4);       // k-blocks 0..3
                t1[u] = tr16(vb0 + (dt * 8 + 4 + hi) * 64 + lo * 4);   // k-blocks 4..7
            }
            asm volatile("s_waitcnt lgkmcnt(0)" ::: "memory");
            __builtin_amdgcn_sched_barrier(0);
            __builtin_amdgcn_s_setprio(1);
#pragma unroll
            for (int u = 0; u < 4; ++u) {
                bf16x8 vf;
#pragma unroll
                for (int j = 0; j < 4; ++j) { vf[j] = t0[u][j]; vf[4 + j] = t1[u][j]; }
                o[dq * 4 + u] = __builtin_amdgcn_mfma_f32_16x16x32_bf16(vf, paf, o[dq * 4 + u], 0, 0, 0);
            }
            __builtin_amdgcn_s_setprio(0);
        }
        __syncthreads();
        buf ^= 1;
    }

    const float invl = 1.0f / l;
    __bf16* cp = ctx + ((size_t)(b * SEQ + q)) * (NH * DHEAD) + h * DHEAD;
#pragma unroll
    for (int dt = 0; dt < 16; ++dt) {
        bf16x4 w;
#pragma unroll
        for (int j = 0; j < 4; ++j) w[j] = (__bf16)(o[dt][j] * invl);
        *(bf16x4*)&cp[dt * 16 + hi * 4] = w;
    }
}

// ---------------------------------------------------------------------------
extern "C" void kernel_launch(void* const* d_in, const int* in_sizes, int n_in,
                              void* d_out, int out_size, void* d_ws, size_t ws_size,
                              hipStream_t stream) {
    const float* hs = (const float*)d_in[0];
    const float* Wq = (const float*)d_in[1];
    const float* Wk = (const float*)d_in[2];
    const float* Wv = (const float*)d_in[3];
    const float* Wo = (const float*)d_in[4];
    const float* qw = (const float*)d_in[5];
    const float* kw = (const float*)d_in[6];
    float* out = (float*)d_out;

    char* ws = (char*)d_ws;
    size_t off = 0;
    auto alloc = [&](size_t bytes) {
        char* p = ws + off;
        off += (bytes + 255) & ~(size_t)255;
        return p;
    };
    const int M = NB * SEQ;                       // 4096
    __bf16* hsB   = (__bf16*)alloc((size_t)M * DMODEL * 2);
    __bf16* WqkvB = (__bf16*)alloc((size_t)4096 * DMODEL * 2);
    __bf16* WoB   = (__bf16*)alloc((size_t)DMODEL * DMODEL * 2);
    float*  QKV   = (float*) alloc((size_t)M * 4096 * 4);
    __bf16* Qb    = (__bf16*)alloc((size_t)M * 2048 * 2);
    __bf16* Kbf   = (__bf16*)alloc((size_t)M * 1024 * 2);
    __bf16* Vbf   = (__bf16*)alloc((size_t)M * 1024 * 2);
    float*  cosT  = (float*) alloc((size_t)SEQ * 128 * 4);
    float*  sinT  = (float*) alloc((size_t)SEQ * 128 * 4);
    __bf16* ctxB  = (__bf16*)QKV;                 // reuse: QKV dead after norm_rope

    rope_tab<<<SEQ, 128, 0, stream>>>(cosT, sinT);
    cvt_f32_bf16<<<8192, 256, 0, stream>>>(hs, hsB, M * DMODEL / 4);
    cvt_f32_bf16<<<4096, 256, 0, stream>>>(Wq, WqkvB, 2048 * 2048 / 4);
    cvt_f32_bf16<<<2048, 256, 0, stream>>>(Wk, WqkvB + (size_t)2048 * 2048, 1024 * 2048 / 4);
    cvt_f32_bf16<<<2048, 256, 0, stream>>>(Wv, WqkvB + (size_t)3072 * 2048, 1024 * 2048 / 4);
    cvt_f32_bf16<<<4096, 256, 0, stream>>>(Wo, WoB, 2048 * 2048 / 4);

    gemm_bt<<<dim3(32, 32), 256, 0, stream>>>(hsB, WqkvB, QKV, M, 4096, DMODEL);

    norm_rope<<<M, 256, 0, stream>>>(QKV, qw, kw, cosT, sinT, Qb, Kbf, Vbf);

    attn3<<<512, 256, 0, stream>>>(Qb, Kbf, Vbf, ctxB);

    gemm_bt<<<dim3(16, 32), 256, 0, stream>>>(ctxB, WoB, out, M, DMODEL, DMODEL);
}

// Round 4
// 258.031 us; speedup vs baseline: 1.7510x; 1.1094x over previous
//
#include <hip/hip_runtime.h>
#include <hip/hip_bf16.h>

// ---------------------------------------------------------------------------
// Gemma sliding-window attention layer, MI355X round 4.
// GEMMs upgraded to 256x256 8-phase pipelined template (T2 swizzle + counted
// vmcnt + raw s_barrier + setprio). attn/norm_rope/cvt unchanged from r3.
// ---------------------------------------------------------------------------

typedef __bf16 bf16x8 __attribute__((ext_vector_type(8)));
typedef __bf16 bf16x4 __attribute__((ext_vector_type(4)));
typedef float f32x4 __attribute__((ext_vector_type(4)));

#define NB 2
#define SEQ 2048
#define DMODEL 2048
#define NH 8
#define NKV 4
#define DHEAD 256
#define SWIN 1024

#define AS1 __attribute__((address_space(1)))
#define AS3 __attribute__((address_space(3)))

static __device__ __forceinline__ void gload_lds16(const void* g, void* l) {
    __builtin_amdgcn_global_load_lds((const AS1 void*)g, (AS3 void*)l, 16, 0, 0);
}

static __device__ __forceinline__ bf16x4 tr16(const __bf16* p) {
    bf16x4 r;
    asm volatile("ds_read_b64_tr_b16 %0, %1" : "=v"(r) : "v"((const AS3 __bf16*)p));
    return r;
}

// ------------------------- f32 -> bf16 convert ------------------------------
__global__ void cvt_f32_bf16(const float* __restrict__ in, __bf16* __restrict__ out, int n4) {
    int i = blockIdx.x * 256 + threadIdx.x;
    if (i >= n4) return;
    f32x4 v = ((const f32x4*)in)[i];
    bf16x4 o;
#pragma unroll
    for (int j = 0; j < 4; ++j) o[j] = (__bf16)v[j];
    ((bf16x4*)out)[i] = o;
}

// ------------------------- RoPE cos/sin table -------------------------------
__global__ void rope_tab(float* __restrict__ cosT, float* __restrict__ sinT) {
    int s = blockIdx.x, i = threadIdx.x;           // i in 0..127
    float fr = (float)s * __expf(-(float)i * 0.0719557843f);  // ln(1e4)/128
    cosT[s * 128 + i] = cosf(fr);
    sinT[s * 128 + i] = sinf(fr);
}

// --------- GEMM 256x256, BK=64, 8-phase pipelined: C = A[M,K] * B[N,K]^T ---
// 8 waves (2Mx4N), per-wave 128x64 output. LDS XOR-swizzled (slot^=row&7,
// 16B units). Stage tile t+2 at phase p3 (buffer reads complete by p2-end
// barrier). Counted vmcnt(8), raw s_barrier only.
__global__ __launch_bounds__(512, 2)
void gemm_bt8(const __bf16* __restrict__ A, const __bf16* __restrict__ B,
              float* __restrict__ C, int M, int N, int K, int nbx) {
    __shared__ __align__(16) __bf16 sA[2][256 * 64];   // 64 KB
    __shared__ __align__(16) __bf16 sB[2][256 * 64];   // 64 KB
    const int tid = threadIdx.x;
    const int wave = tid >> 6, lane = tid & 63;
    const int lo = lane & 15, hi = lane >> 4;
    const int wm = wave >> 2, wn = wave & 3;
    const int qq = (int)gridDim.x >> 3;
    const int swz = ((int)blockIdx.x & 7) * qq + ((int)blockIdx.x >> 3);
    const int bx = swz % nbx, by = swz / nbx;
    const int brow = by * 256, bcol = bx * 256;
    const int xr = lo & 7;

    int aoff[4];
#pragma unroll
    for (int i = 0; i < 4; ++i) {
        int n = i * 512 + tid, r = n >> 3, s = n & 7;
        aoff[i] = r * K + ((s ^ (r & 7)) << 3);   // pre-swizzled global source
    }
    const __bf16* Ab = A + (size_t)brow * K;
    const __bf16* Bb = B + (size_t)bcol * K;

    auto stg = [&](int bsel, int kt) {
        const __bf16* ga = Ab + kt * 64;
        const __bf16* gb = Bb + kt * 64;
#pragma unroll
        for (int i = 0; i < 4; ++i) {
            gload_lds16(ga + aoff[i], (char*)&sA[bsel][0] + (i * 512 + wave * 64) * 16);
            gload_lds16(gb + aoff[i], (char*)&sB[bsel][0] + (i * 512 + wave * 64) * 16);
        }
    };

    f32x4 acc[8][4] = {};
    const int nt = K >> 6;

    stg(0, 0);
    stg(1, 1);
    asm volatile("s_waitcnt vmcnt(8)" ::: "memory");
    __builtin_amdgcn_s_barrier();

    for (int t = 0; t < nt; ++t) {
        const int buf = t & 1;
        const __bf16* sa = &sA[buf][0];
        const __bf16* sb = &sB[buf][0];
        bf16x8 af[8], b0[4], b1[4];
        // ---- p0: read A-half0 (8) + B-half0 (4); MFMA m0-3 x n0-1
#pragma unroll
        for (int m = 0; m < 4; ++m)
#pragma unroll
            for (int ks = 0; ks < 2; ++ks)
                af[m * 2 + ks] = *(const bf16x8*)&sa[(wm * 128 + m * 16 + lo) * 64 + (((ks * 4 + hi) ^ xr) << 3)];
#pragma unroll
        for (int n = 0; n < 2; ++n)
#pragma unroll
            for (int ks = 0; ks < 2; ++ks)
                b0[n * 2 + ks] = *(const bf16x8*)&sb[(wn * 64 + n * 16 + lo) * 64 + (((ks * 4 + hi) ^ xr) << 3)];
        __builtin_amdgcn_sched_barrier(0);
        __builtin_amdgcn_s_barrier();
        __builtin_amdgcn_s_setprio(1);
#pragma unroll
        for (int m = 0; m < 4; ++m)
#pragma unroll
            for (int n = 0; n < 2; ++n)
#pragma unroll
                for (int ks = 0; ks < 2; ++ks)
                    acc[m][n] = __builtin_amdgcn_mfma_f32_16x16x32_bf16(af[m * 2 + ks], b0[n * 2 + ks], acc[m][n], 0, 0, 0);
        __builtin_amdgcn_s_setprio(0);
        __builtin_amdgcn_sched_barrier(0);
        __builtin_amdgcn_s_barrier();
        // ---- p1: read B-half1 (4); MFMA m0-3 x n2-3
#pragma unroll
        for (int n = 0; n < 2; ++n)
#pragma unroll
            for (int ks = 0; ks < 2; ++ks)
                b1[n * 2 + ks] = *(const bf16x8*)&sb[(wn * 64 + (n + 2) * 16 + lo) * 64 + (((ks * 4 + hi) ^ xr) << 3)];
        __builtin_amdgcn_sched_barrier(0);
        __builtin_amdgcn_s_barrier();
        __builtin_amdgcn_s_setprio(1);
#pragma unroll
        for (int m = 0; m < 4; ++m)
#pragma unroll
            for (int n = 0; n < 2; ++n)
#pragma unroll
                for (int ks = 0; ks < 2; ++ks)
                    acc[m][n + 2] = __builtin_amdgcn_mfma_f32_16x16x32_bf16(af[m * 2 + ks], b1[n * 2 + ks], acc[m][n + 2], 0, 0, 0);
        __builtin_amdgcn_s_setprio(0);
        __builtin_amdgcn_sched_barrier(0);
        __builtin_amdgcn_s_barrier();
        // ---- p2: read A-half1 (8); MFMA m4-7 x n2-3  (last reads of buf)
#pragma unroll
        for (int m = 0; m < 4; ++m)
#pragma unroll
            for (int ks = 0; ks < 2; ++ks)
                af[m * 2 + ks] = *(const bf16x8*)&sa[(wm * 128 + (m + 4) * 16 + lo) * 64 + (((ks * 4 + hi) ^ xr) << 3)];
        __builtin_amdgcn_sched_barrier(0);
        __builtin_amdgcn_s_barrier();
        __builtin_amdgcn_s_setprio(1);
#pragma unroll
        for (int m = 0; m < 4; ++m)
#pragma unroll
            for (int n = 0; n < 2; ++n)
#pragma unroll
                for (int ks = 0; ks < 2; ++ks)
                    acc[m + 4][n + 2] = __builtin_amdgcn_mfma_f32_16x16x32_bf16(af[m * 2 + ks], b1[n * 2 + ks], acc[m + 4][n + 2], 0, 0, 0);
        __builtin_amdgcn_s_setprio(0);
        __builtin_amdgcn_sched_barrier(0);
        __builtin_amdgcn_s_barrier();
        // ---- p3: stage tile t+2 into buf (reads of buf all done); MFMA
        //          m4-7 x n0-1; counted vmcnt so t+1's loads have landed.
        if (t + 2 < nt) stg(buf, t + 2);
        __builtin_amdgcn_sched_barrier(0);
        __builtin_amdgcn_s_setprio(1);
#pragma unroll
        for (int m = 0; m < 4; ++m)
#pragma unroll
            for (int n = 0; n < 2; ++n)
#pragma unroll
                for (int ks = 0; ks < 2; ++ks)
                    acc[m + 4][n] = __builtin_amdgcn_mfma_f32_16x16x32_bf16(af[m * 2 + ks], b0[n * 2 + ks], acc[m + 4][n], 0, 0, 0);
        __builtin_amdgcn_s_setprio(0);
        if (t + 2 < nt) asm volatile("s_waitcnt vmcnt(8)" ::: "memory");
        else            asm volatile("s_waitcnt vmcnt(0)" ::: "memory");
        __builtin_amdgcn_sched_barrier(0);
        __builtin_amdgcn_s_barrier();
    }

#pragma unroll
    for (int m = 0; m < 8; ++m) {
        int row = brow + wm * 128 + m * 16 + hi * 4;
#pragma unroll
        for (int n = 0; n < 4; ++n) {
            float* cp = C + (size_t)row * N + bcol + wn * 64 + n * 16 + lo;
#pragma unroll
            for (int j = 0; j < 4; ++j)
                cp[(size_t)j * N] = acc[m][n][j];
        }
    }
}

// ---------- RMSNorm + RoPE (q,k) + V convert, all from QKV f32 -------------
__global__ __launch_bounds__(256)
void norm_rope(const float* __restrict__ QKV, const float* __restrict__ qw,
               const float* __restrict__ kw, const float* __restrict__ cosT,
               const float* __restrict__ sinT, __bf16* __restrict__ Qo,
               __bf16* __restrict__ Ko, __bf16* __restrict__ Vo) {
    const int r = blockIdx.x;            // b*S + s
    const int b = r >> 11, s = r & (SEQ - 1);
    const int wave = threadIdx.x >> 6, lane = threadIdx.x & 63;
    f32x4 cos4 = *(const f32x4*)&cosT[s * 128 + (lane & 31) * 4];
    f32x4 sin4 = *(const f32x4*)&sinT[s * 128 + (lane & 31) * 4];
#pragma unroll
    for (int ii = 0; ii < 4; ++ii) {
        int hh = wave + ii * 4;          // 0..15
        if (hh < 12) {
            bool isq = hh < 8;
            int col0 = isq ? hh * DHEAD : DMODEL + (hh - 8) * DHEAD;
            const float* src = QKV + (size_t)r * 4096 + col0;
            f32x4 x = *(const f32x4*)&src[lane * 4];
            float ss = x[0] * x[0] + x[1] * x[1] + x[2] * x[2] + x[3] * x[3];
#pragma unroll
            for (int d2 = 1; d2 < 64; d2 <<= 1) ss += __shfl_xor(ss, d2);
            float scale = rsqrtf(ss * (1.f / DHEAD) + 1e-6f);
            const float* wp = isq ? qw : kw;
            float nx[4];
#pragma unroll
            for (int j = 0; j < 4; ++j)
                nx[j] = x[j] * scale * (1.f + wp[lane * 4 + j]);
            bf16x4 ov;
#pragma unroll
            for (int j = 0; j < 4; ++j) {
                float other = __shfl_xor(nx[j], 32);
                float rot = (lane < 32) ? -other : other;
                float v = nx[j] * cos4[j] + rot * sin4[j];
                if (isq) v *= 0.0625f;   // SCALE folded into q
                ov[j] = (__bf16)v;
            }
            __bf16* dst = isq ? (Qo + ((size_t)(b * NH + hh) * SEQ + s) * DHEAD)
                              : (Ko + ((size_t)(b * NKV + (hh - 8)) * SEQ + s) * DHEAD);
            *(bf16x4*)&dst[lane * 4] = ov;
        } else {
            int vh = hh - 12;
            const float* src = QKV + (size_t)r * 4096 + 3072 + vh * DHEAD;
            f32x4 x = *(const f32x4*)&src[lane * 4];
            bf16x4 ov;
#pragma unroll
            for (int j = 0; j < 4; ++j) ov[j] = (__bf16)x[j];
            __bf16* dst = Vo + ((size_t)(b * NKV + vh) * SEQ + s) * DHEAD;
            *(bf16x4*)&dst[lane * 4] = ov;
        }
    }
}

// ------------------ flash attention v3 (unchanged from r3) -----------------
__global__ __launch_bounds__(256)
void attn3(const __bf16* __restrict__ Q, const __bf16* __restrict__ Kb,
           const __bf16* __restrict__ Vb, __bf16* __restrict__ ctx) {
    const int bid = blockIdx.x;
    const int bk = bid & 7;            // XCD grouping: same (b,kh) -> same XCD
    const int qt = bid >> 3;
    const int b = bk >> 2, kh = bk & 3;
    const int q0 = qt * 32;
    const int tid = threadIdx.x;
    const int wave = tid >> 6, lane = tid & 63;
    const int lo = lane & 15, hi = lane >> 4;
    const int hsel = wave >> 1, qsub = wave & 1;
    const int h = kh * 2 + hsel;
    const int qbase = q0 + qsub * 16;
    const int q = qbase + lo;

    __shared__ __align__(16) __bf16 kbuf[2][32 * 256];   // 2 x 16 KB
    __shared__ __align__(16) __bf16 vbuf[2][32 * 256];   // 2 x 16 KB

    const __bf16* Qp = Q + ((size_t)(b * NH + h) * SEQ + qbase) * DHEAD;
    const __bf16* Kp = Kb + (size_t)(b * NKV + kh) * SEQ * DHEAD;
    const __bf16* Vp = Vb + (size_t)(b * NKV + kh) * SEQ * DHEAD;

    int koff[4], voff[4];
#pragma unroll
    for (int i = 0; i < 4; ++i) {
        int n = i * 256 + tid;                 // 16B slot index
        int r = n >> 5, c = n & 31;
        koff[i] = r * 256 + ((c ^ (r & 7)) << 3);
        int st = n >> 3, w = n & 7;
        int vk = (st & 7) * 4 + (w >> 1);
        int vd = (st >> 3) * 16 + (w & 1) * 8;
        voff[i] = vk * 256 + vd;
    }

    auto stage = [&](int bsel, int c0) {
        const __bf16* kg = Kp + (size_t)c0 * DHEAD;
        const __bf16* vg = Vp + (size_t)c0 * DHEAD;
        char* kd = (char*)&kbuf[bsel][0] + wave * 1024;
        char* vd = (char*)&vbuf[bsel][0] + wave * 1024;
#pragma unroll
        for (int i = 0; i < 4; ++i) {
            gload_lds16(kg + koff[i], kd + i * 4096);
            gload_lds16(vg + voff[i], vd + i * 4096);
        }
    };

    bf16x8 qf[8];
#pragma unroll
    for (int dc = 0; dc < 8; ++dc)
        qf[dc] = *(const bf16x8*)(Qp + (size_t)lo * DHEAD + dc * 32 + hi * 8);

    f32x4 o[16] = {};
    float m = -3e38f, l = 0.f;

    int kstart = q0 - SWIN; if (kstart < 0) kstart = 0;
    const int nt = (q0 + 32 - kstart) >> 5;

    stage(0, kstart);
    __syncthreads();
    int buf = 0;
    for (int t = 0; t < nt; ++t) {
        const int c0 = kstart + t * 32;
        if (t + 1 < nt) stage(buf ^ 1, c0 + 32);

        f32x4 sc0 = {}, sc1 = {};
        const __bf16* kb0 = &kbuf[buf][0];
        __builtin_amdgcn_s_setprio(1);
#pragma unroll
        for (int dc = 0; dc < 8; ++dc) {
            int u = dc * 4 + hi;
            bf16x8 kfa = *(const bf16x8*)&kb0[lo * 256 + ((u ^ (lo & 7)) << 3)];
            bf16x8 kfb = *(const bf16x8*)&kb0[(16 + lo) * 256 + ((u ^ ((16 + lo) & 7)) << 3)];
            sc0 = __builtin_amdgcn_mfma_f32_16x16x32_bf16(kfa, qf[dc], sc0, 0, 0, 0);
            sc1 = __builtin_amdgcn_mfma_f32_16x16x32_bf16(kfb, qf[dc], sc1, 0, 0, 0);
        }
        __builtin_amdgcn_s_setprio(0);

        float s8[8];
#pragma unroll
        for (int j = 0; j < 4; ++j) {
            int ka = c0 + hi * 4 + j;
            int kb2 = ka + 16;
            s8[j]     = (ka <= q && q - ka < SWIN) ? sc0[j] : -1e30f;
            s8[4 + j] = (kb2 <= q && q - kb2 < SWIN) ? sc1[j] : -1e30f;
        }
        float pm = s8[0];
#pragma unroll
        for (int i = 1; i < 8; ++i) pm = fmaxf(pm, s8[i]);
        pm = fmaxf(pm, __shfl_xor(pm, 16));
        pm = fmaxf(pm, __shfl_xor(pm, 32));
        if (__any(pm > m + 8.f)) {             // T13 defer-max
            float mn = fmaxf(m, pm);
            float corr = __expf(m - mn);
            l *= corr;
#pragma unroll
            for (int dt = 0; dt < 16; ++dt) o[dt] *= corr;
            m = mn;
        }
        float p8[8], ps = 0.f;
#pragma unroll
        for (int i = 0; i < 8; ++i) {
            float e = __expf(s8[i] - m);
            p8[i] = (s8[i] > -9e29f) ? e : 0.f;
            ps += p8[i];
        }
        ps += __shfl_xor(ps, 16);
        ps += __shfl_xor(ps, 32);
        l += ps;

        bf16x8 paf;
#pragma unroll
        for (int i = 0; i < 8; ++i) paf[i] = (__bf16)p8[i];

        const __bf16* vb0 = &vbuf[buf][0];
#pragma unroll
        for (int dq = 0; dq < 4; ++dq) {
            bf16x4 t0[4], t1[4];
#pragma unroll
            for (int u = 0; u < 4; ++u) {
                int dt = dq * 4 + u;
                t0[u] = tr16(vb0 + (dt * 8 + hi) * 64 + lo * 4);       // k-blocks 0..3
                t1[u] = tr16(vb0 + (dt * 8 + 4 + hi) * 64 + lo * 4);   // k-blocks 4..7
            }
            asm volatile("s_waitcnt lgkmcnt(0)" ::: "memory");
            __builtin_amdgcn_sched_barrier(0);
            __builtin_amdgcn_s_setprio(1);
#pragma unroll
            for (int u = 0; u < 4; ++u) {
                bf16x8 vf;
#pragma unroll
                for (int j = 0; j < 4; ++j) { vf[j] = t0[u][j]; vf[4 + j] = t1[u][j]; }
                o[dq * 4 + u] = __builtin_amdgcn_mfma_f32_16x16x32_bf16(vf, paf, o[dq * 4 + u], 0, 0, 0);
            }
            __builtin_amdgcn_s_setprio(0);
        }
        __syncthreads();
        buf ^= 1;
    }

    const float invl = 1.0f / l;
    __bf16* cp = ctx + ((size_t)(b * SEQ + q)) * (NH * DHEAD) + h * DHEAD;
#pragma unroll
    for (int dt = 0; dt < 16; ++dt) {
        bf16x4 w;
#pragma unroll
        for (int j = 0; j < 4; ++j) w[j] = (__bf16)(o[dt][j] * invl);
        *(bf16x4*)&cp[dt * 16 + hi * 4] = w;
    }
}

// ---------------------------------------------------------------------------
extern "C" void kernel_launch(void* const* d_in, const int* in_sizes, int n_in,
                              void* d_out, int out_size, void* d_ws, size_t ws_size,
                              hipStream_t stream) {
    const float* hs = (const float*)d_in[0];
    const float* Wq = (const float*)d_in[1];
    const float* Wk = (const float*)d_in[2];
    const float* Wv = (const float*)d_in[3];
    const float* Wo = (const float*)d_in[4];
    const float* qw = (const float*)d_in[5];
    const float* kw = (const float*)d_in[6];
    float* out = (float*)d_out;

    char* ws = (char*)d_ws;
    size_t off = 0;
    auto alloc = [&](size_t bytes) {
        char* p = ws + off;
        off += (bytes + 255) & ~(size_t)255;
        return p;
    };
    const int M = NB * SEQ;                       // 4096
    __bf16* hsB   = (__bf16*)alloc((size_t)M * DMODEL * 2);
    __bf16* WqkvB = (__bf16*)alloc((size_t)4096 * DMODEL * 2);
    __bf16* WoB   = (__bf16*)alloc((size_t)DMODEL * DMODEL * 2);
    float*  QKV   = (float*) alloc((size_t)M * 4096 * 4);
    __bf16* Qb    = (__bf16*)alloc((size_t)M * 2048 * 2);
    __bf16* Kbf   = (__bf16*)alloc((size_t)M * 1024 * 2);
    __bf16* Vbf   = (__bf16*)alloc((size_t)M * 1024 * 2);
    float*  cosT  = (float*) alloc((size_t)SEQ * 128 * 4);
    float*  sinT  = (float*) alloc((size_t)SEQ * 128 * 4);
    __bf16* ctxB  = (__bf16*)QKV;                 // reuse: QKV dead after norm_rope

    rope_tab<<<SEQ, 128, 0, stream>>>(cosT, sinT);
    cvt_f32_bf16<<<8192, 256, 0, stream>>>(hs, hsB, M * DMODEL / 4);
    cvt_f32_bf16<<<4096, 256, 0, stream>>>(Wq, WqkvB, 2048 * 2048 / 4);
    cvt_f32_bf16<<<2048, 256, 0, stream>>>(Wk, WqkvB + (size_t)2048 * 2048, 1024 * 2048 / 4);
    cvt_f32_bf16<<<2048, 256, 0, stream>>>(Wv, WqkvB + (size_t)3072 * 2048, 1024 * 2048 / 4);
    cvt_f32_bf16<<<4096, 256, 0, stream>>>(Wo, WoB, 2048 * 2048 / 4);

    // fused QKV projection: 256 blocks (16x16 tiles of 256)
    gemm_bt8<<<256, 512, 0, stream>>>(hsB, WqkvB, QKV, M, 4096, DMODEL, 16);

    norm_rope<<<M, 256, 0, stream>>>(QKV, qw, kw, cosT, sinT, Qb, Kbf, Vbf);

    attn3<<<512, 256, 0, stream>>>(Qb, Kbf, Vbf, ctxB);

    // output projection: 128 blocks (8x16 tiles of 256)
    gemm_bt8<<<128, 512, 0, stream>>>(ctxB, WoB, out, M, DMODEL, DMODEL, 8);
}

// Round 6
// 247.461 us; speedup vs baseline: 1.8257x; 1.0427x over previous
//
#include <hip/hip_runtime.h>
#include <hip/hip_bf16.h>

// ---------------------------------------------------------------------------
// Gemma sliding-window attention layer, MI355X round 6.
// attn5 = r4's proven attn3 structure (__syncthreads sync, shfl_xor softmax,
// per-group lgkmcnt(0) PV) + V single-buffered (48KB LDS -> 3 blocks/CU)
// + heavy-first dispatch. r5's bundled counted-vmcnt/permlane changes
// reverted (failed correctness; bisecting).
// GEMMs (256x256 8-phase), norm_rope, cvt unchanged from round 4.
// ---------------------------------------------------------------------------

typedef __bf16 bf16x8 __attribute__((ext_vector_type(8)));
typedef __bf16 bf16x4 __attribute__((ext_vector_type(4)));
typedef float f32x4 __attribute__((ext_vector_type(4)));

#define NB 2
#define SEQ 2048
#define DMODEL 2048
#define NH 8
#define NKV 4
#define DHEAD 256
#define SWIN 1024

#define AS1 __attribute__((address_space(1)))
#define AS3 __attribute__((address_space(3)))

static __device__ __forceinline__ void gload_lds16(const void* g, void* l) {
    __builtin_amdgcn_global_load_lds((const AS1 void*)g, (AS3 void*)l, 16, 0, 0);
}

static __device__ __forceinline__ bf16x4 tr16(const __bf16* p) {
    bf16x4 r;
    asm volatile("ds_read_b64_tr_b16 %0, %1" : "=v"(r) : "v"((const AS3 __bf16*)p));
    return r;
}

// ------------------------- f32 -> bf16 convert ------------------------------
__global__ void cvt_f32_bf16(const float* __restrict__ in, __bf16* __restrict__ out, int n4) {
    int i = blockIdx.x * 256 + threadIdx.x;
    if (i >= n4) return;
    f32x4 v = ((const f32x4*)in)[i];
    bf16x4 o;
#pragma unroll
    for (int j = 0; j < 4; ++j) o[j] = (__bf16)v[j];
    ((bf16x4*)out)[i] = o;
}

// ------------------------- RoPE cos/sin table -------------------------------
__global__ void rope_tab(float* __restrict__ cosT, float* __restrict__ sinT) {
    int s = blockIdx.x, i = threadIdx.x;           // i in 0..127
    float fr = (float)s * __expf(-(float)i * 0.0719557843f);  // ln(1e4)/128
    cosT[s * 128 + i] = cosf(fr);
    sinT[s * 128 + i] = sinf(fr);
}

// --------- GEMM 256x256, BK=64, 8-phase pipelined: C = A[M,K] * B[N,K]^T ---
__global__ __launch_bounds__(512, 2)
void gemm_bt8(const __bf16* __restrict__ A, const __bf16* __restrict__ B,
              float* __restrict__ C, int M, int N, int K, int nbx) {
    __shared__ __align__(16) __bf16 sA[2][256 * 64];   // 64 KB
    __shared__ __align__(16) __bf16 sB[2][256 * 64];   // 64 KB
    const int tid = threadIdx.x;
    const int wave = tid >> 6, lane = tid & 63;
    const int lo = lane & 15, hi = lane >> 4;
    const int wm = wave >> 2, wn = wave & 3;
    const int qq = (int)gridDim.x >> 3;
    const int swz = ((int)blockIdx.x & 7) * qq + ((int)blockIdx.x >> 3);
    const int bx = swz % nbx, by = swz / nbx;
    const int brow = by * 256, bcol = bx * 256;
    const int xr = lo & 7;

    int aoff[4];
#pragma unroll
    for (int i = 0; i < 4; ++i) {
        int n = i * 512 + tid, r = n >> 3, s = n & 7;
        aoff[i] = r * K + ((s ^ (r & 7)) << 3);   // pre-swizzled global source
    }
    const __bf16* Ab = A + (size_t)brow * K;
    const __bf16* Bb = B + (size_t)bcol * K;

    auto stg = [&](int bsel, int kt) {
        const __bf16* ga = Ab + kt * 64;
        const __bf16* gb = Bb + kt * 64;
#pragma unroll
        for (int i = 0; i < 4; ++i) {
            gload_lds16(ga + aoff[i], (char*)&sA[bsel][0] + (i * 512 + wave * 64) * 16);
            gload_lds16(gb + aoff[i], (char*)&sB[bsel][0] + (i * 512 + wave * 64) * 16);
        }
    };

    f32x4 acc[8][4] = {};
    const int nt = K >> 6;

    stg(0, 0);
    stg(1, 1);
    asm volatile("s_waitcnt vmcnt(8)" ::: "memory");
    __builtin_amdgcn_s_barrier();

    for (int t = 0; t < nt; ++t) {
        const int buf = t & 1;
        const __bf16* sa = &sA[buf][0];
        const __bf16* sb = &sB[buf][0];
        bf16x8 af[8], b0[4], b1[4];
        // ---- p0: read A-half0 (8) + B-half0 (4); MFMA m0-3 x n0-1
#pragma unroll
        for (int m = 0; m < 4; ++m)
#pragma unroll
            for (int ks = 0; ks < 2; ++ks)
                af[m * 2 + ks] = *(const bf16x8*)&sa[(wm * 128 + m * 16 + lo) * 64 + (((ks * 4 + hi) ^ xr) << 3)];
#pragma unroll
        for (int n = 0; n < 2; ++n)
#pragma unroll
            for (int ks = 0; ks < 2; ++ks)
                b0[n * 2 + ks] = *(const bf16x8*)&sb[(wn * 64 + n * 16 + lo) * 64 + (((ks * 4 + hi) ^ xr) << 3)];
        __builtin_amdgcn_sched_barrier(0);
        __builtin_amdgcn_s_barrier();
        __builtin_amdgcn_s_setprio(1);
#pragma unroll
        for (int m = 0; m < 4; ++m)
#pragma unroll
            for (int n = 0; n < 2; ++n)
#pragma unroll
                for (int ks = 0; ks < 2; ++ks)
                    acc[m][n] = __builtin_amdgcn_mfma_f32_16x16x32_bf16(af[m * 2 + ks], b0[n * 2 + ks], acc[m][n], 0, 0, 0);
        __builtin_amdgcn_s_setprio(0);
        __builtin_amdgcn_sched_barrier(0);
        __builtin_amdgcn_s_barrier();
        // ---- p1: read B-half1 (4); MFMA m0-3 x n2-3
#pragma unroll
        for (int n = 0; n < 2; ++n)
#pragma unroll
            for (int ks = 0; ks < 2; ++ks)
                b1[n * 2 + ks] = *(const bf16x8*)&sb[(wn * 64 + (n + 2) * 16 + lo) * 64 + (((ks * 4 + hi) ^ xr) << 3)];
        __builtin_amdgcn_sched_barrier(0);
        __builtin_amdgcn_s_barrier();
        __builtin_amdgcn_s_setprio(1);
#pragma unroll
        for (int m = 0; m < 4; ++m)
#pragma unroll
            for (int n = 0; n < 2; ++n)
#pragma unroll
                for (int ks = 0; ks < 2; ++ks)
                    acc[m][n + 2] = __builtin_amdgcn_mfma_f32_16x16x32_bf16(af[m * 2 + ks], b1[n * 2 + ks], acc[m][n + 2], 0, 0, 0);
        __builtin_amdgcn_s_setprio(0);
        __builtin_amdgcn_sched_barrier(0);
        __builtin_amdgcn_s_barrier();
        // ---- p2: read A-half1 (8); MFMA m4-7 x n2-3  (last reads of buf)
#pragma unroll
        for (int m = 0; m < 4; ++m)
#pragma unroll
            for (int ks = 0; ks < 2; ++ks)
                af[m * 2 + ks] = *(const bf16x8*)&sa[(wm * 128 + (m + 4) * 16 + lo) * 64 + (((ks * 4 + hi) ^ xr) << 3)];
        __builtin_amdgcn_sched_barrier(0);
        __builtin_amdgcn_s_barrier();
        __builtin_amdgcn_s_setprio(1);
#pragma unroll
        for (int m = 0; m < 4; ++m)
#pragma unroll
            for (int n = 0; n < 2; ++n)
#pragma unroll
                for (int ks = 0; ks < 2; ++ks)
                    acc[m + 4][n + 2] = __builtin_amdgcn_mfma_f32_16x16x32_bf16(af[m * 2 + ks], b1[n * 2 + ks], acc[m + 4][n + 2], 0, 0, 0);
        __builtin_amdgcn_s_setprio(0);
        __builtin_amdgcn_sched_barrier(0);
        __builtin_amdgcn_s_barrier();
        // ---- p3: stage tile t+2 into buf; MFMA m4-7 x n0-1; counted vmcnt
        if (t + 2 < nt) stg(buf, t + 2);
        __builtin_amdgcn_sched_barrier(0);
        __builtin_amdgcn_s_setprio(1);
#pragma unroll
        for (int m = 0; m < 4; ++m)
#pragma unroll
            for (int n = 0; n < 2; ++n)
#pragma unroll
                for (int ks = 0; ks < 2; ++ks)
                    acc[m + 4][n] = __builtin_amdgcn_mfma_f32_16x16x32_bf16(af[m * 2 + ks], b0[n * 2 + ks], acc[m + 4][n], 0, 0, 0);
        __builtin_amdgcn_s_setprio(0);
        if (t + 2 < nt) asm volatile("s_waitcnt vmcnt(8)" ::: "memory");
        else            asm volatile("s_waitcnt vmcnt(0)" ::: "memory");
        __builtin_amdgcn_sched_barrier(0);
        __builtin_amdgcn_s_barrier();
    }

#pragma unroll
    for (int m = 0; m < 8; ++m) {
        int row = brow + wm * 128 + m * 16 + hi * 4;
#pragma unroll
        for (int n = 0; n < 4; ++n) {
            float* cp = C + (size_t)row * N + bcol + wn * 64 + n * 16 + lo;
#pragma unroll
            for (int j = 0; j < 4; ++j)
                cp[(size_t)j * N] = acc[m][n][j];
        }
    }
}

// ---------- RMSNorm + RoPE (q,k) + V convert, all from QKV f32 -------------
__global__ __launch_bounds__(256)
void norm_rope(const float* __restrict__ QKV, const float* __restrict__ qw,
               const float* __restrict__ kw, const float* __restrict__ cosT,
               const float* __restrict__ sinT, __bf16* __restrict__ Qo,
               __bf16* __restrict__ Ko, __bf16* __restrict__ Vo) {
    const int r = blockIdx.x;            // b*S + s
    const int b = r >> 11, s = r & (SEQ - 1);
    const int wave = threadIdx.x >> 6, lane = threadIdx.x & 63;
    f32x4 cos4 = *(const f32x4*)&cosT[s * 128 + (lane & 31) * 4];
    f32x4 sin4 = *(const f32x4*)&sinT[s * 128 + (lane & 31) * 4];
#pragma unroll
    for (int ii = 0; ii < 4; ++ii) {
        int hh = wave + ii * 4;          // 0..15
        if (hh < 12) {
            bool isq = hh < 8;
            int col0 = isq ? hh * DHEAD : DMODEL + (hh - 8) * DHEAD;
            const float* src = QKV + (size_t)r * 4096 + col0;
            f32x4 x = *(const f32x4*)&src[lane * 4];
            float ss = x[0] * x[0] + x[1] * x[1] + x[2] * x[2] + x[3] * x[3];
#pragma unroll
            for (int d2 = 1; d2 < 64; d2 <<= 1) ss += __shfl_xor(ss, d2);
            float scale = rsqrtf(ss * (1.f / DHEAD) + 1e-6f);
            const float* wp = isq ? qw : kw;
            float nx[4];
#pragma unroll
            for (int j = 0; j < 4; ++j)
                nx[j] = x[j] * scale * (1.f + wp[lane * 4 + j]);
            bf16x4 ov;
#pragma unroll
            for (int j = 0; j < 4; ++j) {
                float other = __shfl_xor(nx[j], 32);
                float rot = (lane < 32) ? -other : other;
                float v = nx[j] * cos4[j] + rot * sin4[j];
                if (isq) v *= 0.0625f;   // SCALE folded into q
                ov[j] = (__bf16)v;
            }
            __bf16* dst = isq ? (Qo + ((size_t)(b * NH + hh) * SEQ + s) * DHEAD)
                              : (Ko + ((size_t)(b * NKV + (hh - 8)) * SEQ + s) * DHEAD);
            *(bf16x4*)&dst[lane * 4] = ov;
        } else {
            int vh = hh - 12;
            const float* src = QKV + (size_t)r * 4096 + 3072 + vh * DHEAD;
            f32x4 x = *(const f32x4*)&src[lane * 4];
            bf16x4 ov;
#pragma unroll
            for (int j = 0; j < 4; ++j) ov[j] = (__bf16)x[j];
            __bf16* dst = Vo + ((size_t)(b * NKV + vh) * SEQ + s) * DHEAD;
            *(bf16x4*)&dst[lane * 4] = ov;
        }
    }
}

// ------------------ flash attention v5 -------------------------------------
// r4's proven attn3 structure; V single-buffered (48KB total -> 3 blocks/CU).
// Per tile: stageV(t)+stageK(t+1) issued right after the barrier that ended
// PV(t-1) (no readers of vbuf remain); mid __syncthreads drains them before
// PV(t); end __syncthreads retires PV reads before next stageV.
__global__ __launch_bounds__(256)
void attn5(const __bf16* __restrict__ Q, const __bf16* __restrict__ Kb,
           const __bf16* __restrict__ Vb, __bf16* __restrict__ ctx) {
    const int bid = blockIdx.x;
    const int bk = bid & 7;            // XCD grouping: same (b,kh) -> same XCD
    const int qt = 63 - (bid >> 3);    // heavy blocks dispatch first
    const int b = bk >> 2, kh = bk & 3;
    const int q0 = qt * 32;
    const int tid = threadIdx.x;
    const int wave = tid >> 6, lane = tid & 63;
    const int lo = lane & 15, hi = lane >> 4;
    const int hsel = wave >> 1, qsub = wave & 1;
    const int h = kh * 2 + hsel;
    const int qbase = q0 + qsub * 16;
    const int q = qbase + lo;

    __shared__ __align__(16) __bf16 kbuf[2][32 * 256];   // 2 x 16 KB
    __shared__ __align__(16) __bf16 vbuf[32 * 256];      // 16 KB single

    const __bf16* Qp = Q + ((size_t)(b * NH + h) * SEQ + qbase) * DHEAD;
    const __bf16* Kp = Kb + (size_t)(b * NKV + kh) * SEQ * DHEAD;
    const __bf16* Vp = Vb + (size_t)(b * NKV + kh) * SEQ * DHEAD;

    int koff[4], voff[4];
#pragma unroll
    for (int i = 0; i < 4; ++i) {
        int n = i * 256 + tid;                 // 16B slot index
        int r = n >> 5, c = n & 31;
        koff[i] = r * 256 + ((c ^ (r & 7)) << 3);
        int st = n >> 3, w = n & 7;
        int vk = (st & 7) * 4 + (w >> 1);
        int vd = (st >> 3) * 16 + (w & 1) * 8;
        voff[i] = vk * 256 + vd;
    }

    auto stageK = [&](int bsel, int c0) {
        const __bf16* kg = Kp + (size_t)c0 * DHEAD;
        char* kd = (char*)&kbuf[bsel][0] + wave * 1024;
#pragma unroll
        for (int i = 0; i < 4; ++i) gload_lds16(kg + koff[i], kd + i * 4096);
    };
    auto stageV = [&](int c0) {
        const __bf16* vg = Vp + (size_t)c0 * DHEAD;
        char* vd = (char*)&vbuf[0] + wave * 1024;
#pragma unroll
        for (int i = 0; i < 4; ++i) gload_lds16(vg + voff[i], vd + i * 4096);
    };

    bf16x8 qf[8];
#pragma unroll
    for (int dc = 0; dc < 8; ++dc)
        qf[dc] = *(const bf16x8*)(Qp + (size_t)lo * DHEAD + dc * 32 + hi * 8);

    f32x4 o[16] = {};
    float m = -3e38f, l = 0.f;

    int kstart = q0 - SWIN; if (kstart < 0) kstart = 0;
    const int nt = (q0 + 32 - kstart) >> 5;

    stageK(0, kstart);
    __syncthreads();                     // K(0) resident (full drain)
    int buf = 0;
    for (int t = 0; t < nt; ++t) {
        const int c0 = kstart + t * 32;
        stageV(c0);                      // vbuf has no readers (post-barrier)
        if (t + 1 < nt) stageK(buf ^ 1, c0 + 32);

        // ---- QK^T (swapped): keys c0+hi*4+j (sc0) / +16 (sc1), q = lo
        f32x4 sc0 = {}, sc1 = {};
        const __bf16* kb0 = &kbuf[buf][0];
        __builtin_amdgcn_s_setprio(1);
#pragma unroll
        for (int dc = 0; dc < 8; ++dc) {
            int u = dc * 4 + hi;
            bf16x8 kfa = *(const bf16x8*)&kb0[lo * 256 + ((u ^ (lo & 7)) << 3)];
            bf16x8 kfb = *(const bf16x8*)&kb0[(16 + lo) * 256 + ((u ^ ((16 + lo) & 7)) << 3)];
            sc0 = __builtin_amdgcn_mfma_f32_16x16x32_bf16(kfa, qf[dc], sc0, 0, 0, 0);
            sc1 = __builtin_amdgcn_mfma_f32_16x16x32_bf16(kfb, qf[dc], sc1, 0, 0, 0);
        }
        __builtin_amdgcn_s_setprio(0);

        // ---- mask + lane-parallel online softmax (state keyed q = lo)
        float s8[8];
#pragma unroll
        for (int j = 0; j < 4; ++j) {
            int ka = c0 + hi * 4 + j;
            int kb2 = ka + 16;
            s8[j]     = (ka <= q && q - ka < SWIN) ? sc0[j] : -1e30f;
            s8[4 + j] = (kb2 <= q && q - kb2 < SWIN) ? sc1[j] : -1e30f;
        }
        float pm = s8[0];
#pragma unroll
        for (int i = 1; i < 8; ++i) pm = fmaxf(pm, s8[i]);
        pm = fmaxf(pm, __shfl_xor(pm, 16));
        pm = fmaxf(pm, __shfl_xor(pm, 32));
        if (__any(pm > m + 8.f)) {             // T13 defer-max
            float mn = fmaxf(m, pm);
            float corr = __expf(m - mn);
            l *= corr;
#pragma unroll
            for (int dt = 0; dt < 16; ++dt) o[dt] *= corr;
            m = mn;
        }
        float p8[8], ps = 0.f;
#pragma unroll
        for (int i = 0; i < 8; ++i) {
            float e = __expf(s8[i] - m);
            p8[i] = (s8[i] > -9e29f) ? e : 0.f;
            ps += p8[i];
        }
        ps += __shfl_xor(ps, 16);
        ps += __shfl_xor(ps, 32);
        l += ps;

        bf16x8 paf;
#pragma unroll
        for (int i = 0; i < 8; ++i) paf[i] = (__bf16)p8[i];

        __syncthreads();                 // V(t) + K(t+1) resident; K reads done

        // ---- PV: o[dt][j] = O^T[d = dt*16+hi*4+j][q = lo]
        const __bf16* vb0 = &vbuf[0];
#pragma unroll
        for (int dq = 0; dq < 4; ++dq) {
            bf16x4 t0[4], t1[4];
#pragma unroll
            for (int u = 0; u < 4; ++u) {
                int dt = dq * 4 + u;
                t0[u] = tr16(vb0 + (dt * 8 + hi) * 64 + lo * 4);       // k-blocks 0..3
                t1[u] = tr16(vb0 + (dt * 8 + 4 + hi) * 64 + lo * 4);   // k-blocks 4..7
            }
            asm volatile("s_waitcnt lgkmcnt(0)" ::: "memory");
            __builtin_amdgcn_sched_barrier(0);
            __builtin_amdgcn_s_setprio(1);
#pragma unroll
            for (int u = 0; u < 4; ++u) {
                bf16x8 vf;
#pragma unroll
                for (int j = 0; j < 4; ++j) { vf[j] = t0[u][j]; vf[4 + j] = t1[u][j]; }
                o[dq * 4 + u] = __builtin_amdgcn_mfma_f32_16x16x32_bf16(vf, paf, o[dq * 4 + u], 0, 0, 0);
            }
            __builtin_amdgcn_s_setprio(0);
        }
        __syncthreads();                 // PV reads retired -> next stageV safe
        buf ^= 1;
    }

    const float invl = 1.0f / l;
    __bf16* cp = ctx + ((size_t)(b * SEQ + q)) * (NH * DHEAD) + h * DHEAD;
#pragma unroll
    for (int dt = 0; dt < 16; ++dt) {
        bf16x4 w;
#pragma unroll
        for (int j = 0; j < 4; ++j) w[j] = (__bf16)(o[dt][j] * invl);
        *(bf16x4*)&cp[dt * 16 + hi * 4] = w;
    }
}

// ---------------------------------------------------------------------------
extern "C" void kernel_launch(void* const* d_in, const int* in_sizes, int n_in,
                              void* d_out, int out_size, void* d_ws, size_t ws_size,
                              hipStream_t stream) {
    const float* hs = (const float*)d_in[0];
    const float* Wq = (const float*)d_in[1];
    const float* Wk = (const float*)d_in[2];
    const float* Wv = (const float*)d_in[3];
    const float* Wo = (const float*)d_in[4];
    const float* qw = (const float*)d_in[5];
    const float* kw = (const float*)d_in[6];
    float* out = (float*)d_out;

    char* ws = (char*)d_ws;
    size_t off = 0;
    auto alloc = [&](size_t bytes) {
        char* p = ws + off;
        off += (bytes + 255) & ~(size_t)255;
        return p;
    };
    const int M = NB * SEQ;                       // 4096
    __bf16* hsB   = (__bf16*)alloc((size_t)M * DMODEL * 2);
    __bf16* WqkvB = (__bf16*)alloc((size_t)4096 * DMODEL * 2);
    __bf16* WoB   = (__bf16*)alloc((size_t)DMODEL * DMODEL * 2);
    float*  QKV   = (float*) alloc((size_t)M * 4096 * 4);
    __bf16* Qb    = (__bf16*)alloc((size_t)M * 2048 * 2);
    __bf16* Kbf   = (__bf16*)alloc((size_t)M * 1024 * 2);
    __bf16* Vbf   = (__bf16*)alloc((size_t)M * 1024 * 2);
    float*  cosT  = (float*) alloc((size_t)SEQ * 128 * 4);
    float*  sinT  = (float*) alloc((size_t)SEQ * 128 * 4);
    __bf16* ctxB  = (__bf16*)QKV;                 // reuse: QKV dead after norm_rope

    rope_tab<<<SEQ, 128, 0, stream>>>(cosT, sinT);
    cvt_f32_bf16<<<8192, 256, 0, stream>>>(hs, hsB, M * DMODEL / 4);
    cvt_f32_bf16<<<4096, 256, 0, stream>>>(Wq, WqkvB, 2048 * 2048 / 4);
    cvt_f32_bf16<<<2048, 256, 0, stream>>>(Wk, WqkvB + (size_t)2048 * 2048, 1024 * 2048 / 4);
    cvt_f32_bf16<<<2048, 256, 0, stream>>>(Wv, WqkvB + (size_t)3072 * 2048, 1024 * 2048 / 4);
    cvt_f32_bf16<<<4096, 256, 0, stream>>>(Wo, WoB, 2048 * 2048 / 4);

    // fused QKV projection: 256 blocks (16x16 tiles of 256)
    gemm_bt8<<<256, 512, 0, stream>>>(hsB, WqkvB, QKV, M, 4096, DMODEL, 16);

    norm_rope<<<M, 256, 0, stream>>>(QKV, qw, kw, cosT, sinT, Qb, Kbf, Vbf);

    attn5<<<512, 256, 0, stream>>>(Qb, Kbf, Vbf, ctxB);

    // output projection: 128 blocks (8x16 tiles of 256)
    gemm_bt8<<<128, 512, 0, stream>>>(ctxB, WoB, out, M, DMODEL, DMODEL, 8);
}

// Round 8
// 216.879 us; speedup vs baseline: 2.0832x; 1.1410x over previous
//
#include <hip/hip_runtime.h>
#include <hip/hip_bf16.h>

// ---------------------------------------------------------------------------
// Gemma sliding-window attention layer, MI355X round 8.
// Fix of r7's staging WAR race: A stage-sets regrouped to match the phase
// read-sets (bt8: slots {0,2}@g1 / {1,3}@g3; bt8n: B@g2, A@g3).
// attn5 / norm_rope frozen from round 6. cvt merged (verified).
// ---------------------------------------------------------------------------

typedef __bf16 bf16x8 __attribute__((ext_vector_type(8)));
typedef __bf16 bf16x4 __attribute__((ext_vector_type(4)));
typedef float f32x4 __attribute__((ext_vector_type(4)));

#define NB 2
#define SEQ 2048
#define DMODEL 2048
#define NH 8
#define NKV 4
#define DHEAD 256
#define SWIN 1024

#define AS1 __attribute__((address_space(1)))
#define AS3 __attribute__((address_space(3)))

static __device__ __forceinline__ void gload_lds16(const void* g, void* l) {
    __builtin_amdgcn_global_load_lds((const AS1 void*)g, (AS3 void*)l, 16, 0, 0);
}

static __device__ __forceinline__ bf16x4 tr16(const __bf16* p) {
    bf16x4 r;
    asm volatile("ds_read_b64_tr_b16 %0, %1" : "=v"(r) : "v"((const AS3 __bf16*)p));
    return r;
}

// ------------------------- merged f32 -> bf16 convert -----------------------
// regions (f32x4 units): hs 2097152 | Wq 1048576 | Wk 524288 | Wv 524288 | Wo 1048576
__global__ void cvt_all(const float* __restrict__ s0, const float* __restrict__ s1,
                        const float* __restrict__ s2, const float* __restrict__ s3,
                        const float* __restrict__ s4, __bf16* __restrict__ d0,
                        __bf16* __restrict__ d1, __bf16* __restrict__ d2,
                        __bf16* __restrict__ d3, __bf16* __restrict__ d4) {
    int i = blockIdx.x * 256 + threadIdx.x;      // grid covers exactly 5242880
    const float* src; __bf16* dst;
    if (i < 2097152) { src = s0; dst = d0; }
    else if (i < 3145728) { i -= 2097152; src = s1; dst = d1; }
    else if (i < 3670016) { i -= 3145728; src = s2; dst = d2; }
    else if (i < 4194304) { i -= 3670016; src = s3; dst = d3; }
    else                  { i -= 4194304; src = s4; dst = d4; }
    f32x4 v = ((const f32x4*)src)[i];
    bf16x4 o;
#pragma unroll
    for (int j = 0; j < 4; ++j) o[j] = (__bf16)v[j];
    ((bf16x4*)dst)[i] = o;
}

// ------------------------- RoPE cos/sin table -------------------------------
__global__ void rope_tab(float* __restrict__ cosT, float* __restrict__ sinT) {
    int s = blockIdx.x, i = threadIdx.x;           // i in 0..127
    float fr = (float)s * __expf(-(float)i * 0.0719557843f);  // ln(1e4)/128
    cosT[s * 128 + i] = cosf(fr);
    sinT[s * 128 + i] = sinf(fr);
}

// --------- GEMM 256x256, BK=64, 8-phase pipelined: C = A[M,K] * B[N,K]^T ---
// 8 waves (2Mx4N), per-wave 128x64. A LDS slot i = rows [64i,64i+64).
// g0 reads A slots {0,2} (rows wm*128+0..63); g2 reads slots {1,3}.
// Stage sets match: A{0,2}@g1, B{2,3}@g2, A{1,3}+B{0,1}@g3. vmcnt(8)@g3-end.
__global__ __launch_bounds__(512, 2)
void gemm_bt8(const __bf16* __restrict__ A, const __bf16* __restrict__ B,
              float* __restrict__ C, int M, int N, int K, int nbx) {
    __shared__ __align__(16) __bf16 sA[2][256 * 64];   // 64 KB
    __shared__ __align__(16) __bf16 sB[2][256 * 64];   // 64 KB
    const int tid = threadIdx.x;
    const int wave = tid >> 6, lane = tid & 63;
    const int lo = lane & 15, hi = lane >> 4;
    const int wm = wave >> 2, wn = wave & 3;
    const int qq = (int)gridDim.x >> 3;
    const int swz = ((int)blockIdx.x & 7) * qq + ((int)blockIdx.x >> 3);
    const int bx = swz % nbx, by = swz / nbx;
    const int brow = by * 256, bcol = bx * 256;
    const int xr = lo & 7;

    int aoff[4];
#pragma unroll
    for (int i = 0; i < 4; ++i) {
        int n = i * 512 + tid, r = n >> 3, s = n & 7;
        aoff[i] = r * K + ((s ^ (r & 7)) << 3);   // pre-swizzled global source
    }
    const __bf16* Ab = A + (size_t)brow * K;
    const __bf16* Bb = B + (size_t)bcol * K;

    // A stage-set h stages slots {h, h+2}: exactly the rows whose ds_reads
    // complete by end of phase g0 (h=0) / g2 (h=1), for BOTH wm halves.
    auto stgA = [&](int bsel, int kt, int h) {
        const __bf16* ga = Ab + kt * 64;
#pragma unroll
        for (int ii = 0; ii < 2; ++ii) {
            int i = h + ii * 2;
            gload_lds16(ga + aoff[i], (char*)&sA[bsel][0] + (i * 512 + wave * 64) * 16);
        }
    };
    // B stage-set h stages slots {2h, 2h+1}; all B reads complete by g1-end.
    auto stgB = [&](int bsel, int kt, int h) {
        const __bf16* gb = Bb + kt * 64;
#pragma unroll
        for (int i = 2 * h; i < 2 * h + 2; ++i)
            gload_lds16(gb + aoff[i], (char*)&sB[bsel][0] + (i * 512 + wave * 64) * 16);
    };

    f32x4 acc[8][4] = {};
    const int nt = K >> 6;

    stgA(0, 0, 0); stgA(0, 0, 1); stgB(0, 0, 0); stgB(0, 0, 1);
    stgA(1, 1, 0); stgA(1, 1, 1); stgB(1, 1, 0); stgB(1, 1, 1);
    asm volatile("s_waitcnt vmcnt(8)" ::: "memory");   // tile0 landed
    __builtin_amdgcn_s_barrier();

    for (int t = 0; t < nt; ++t) {
        const int buf = t & 1;
        const bool pre = (t + 2 < nt);
        const __bf16* sa = &sA[buf][0];
        const __bf16* sb = &sB[buf][0];
        bf16x8 af[8], b0[4], b1[4];
        // ---- g0: ds_read A rows wm*128+0..63 (slots {0,2}) + B-nh0; MFMA Q0
#pragma unroll
        for (int m = 0; m < 4; ++m)
#pragma unroll
            for (int ks = 0; ks < 2; ++ks)
                af[m * 2 + ks] = *(const bf16x8*)&sa[(wm * 128 + m * 16 + lo) * 64 + (((ks * 4 + hi) ^ xr) << 3)];
#pragma unroll
        for (int n = 0; n < 2; ++n)
#pragma unroll
            for (int ks = 0; ks < 2; ++ks)
                b0[n * 2 + ks] = *(const bf16x8*)&sb[(wn * 64 + n * 16 + lo) * 64 + (((ks * 4 + hi) ^ xr) << 3)];
        __builtin_amdgcn_sched_barrier(0);
        __builtin_amdgcn_s_barrier();
        __builtin_amdgcn_s_setprio(1);
#pragma unroll
        for (int m = 0; m < 4; ++m)
#pragma unroll
            for (int n = 0; n < 2; ++n)
#pragma unroll
                for (int ks = 0; ks < 2; ++ks)
                    acc[m][n] = __builtin_amdgcn_mfma_f32_16x16x32_bf16(af[m * 2 + ks], b0[n * 2 + ks], acc[m][n], 0, 0, 0);
        __builtin_amdgcn_s_setprio(0);
        __builtin_amdgcn_sched_barrier(0);
        __builtin_amdgcn_s_barrier();
        // ---- g1: ds_read B-nh1; stage A-set0(t+2) (slots {0,2}, read-done); MFMA Q1
#pragma unroll
        for (int n = 0; n < 2; ++n)
#pragma unroll
            for (int ks = 0; ks < 2; ++ks)
                b1[n * 2 + ks] = *(const bf16x8*)&sb[(wn * 64 + (n + 2) * 16 + lo) * 64 + (((ks * 4 + hi) ^ xr) << 3)];
        if (pre) stgA(buf, t + 2, 0);
        __builtin_amdgcn_sched_barrier(0);
        __builtin_amdgcn_s_barrier();
        __builtin_amdgcn_s_setprio(1);
#pragma unroll
        for (int m = 0; m < 4; ++m)
#pragma unroll
            for (int n = 0; n < 2; ++n)
#pragma unroll
                for (int ks = 0; ks < 2; ++ks)
                    acc[m][n + 2] = __builtin_amdgcn_mfma_f32_16x16x32_bf16(af[m * 2 + ks], b1[n * 2 + ks], acc[m][n + 2], 0, 0, 0);
        __builtin_amdgcn_s_setprio(0);
        __builtin_amdgcn_sched_barrier(0);
        __builtin_amdgcn_s_barrier();
        // ---- g2: ds_read A rows wm*128+64..127 (slots {1,3}); stage B{2,3}(t+2); MFMA Q2
#pragma unroll
        for (int m = 0; m < 4; ++m)
#pragma unroll
            for (int ks = 0; ks < 2; ++ks)
                af[m * 2 + ks] = *(const bf16x8*)&sa[(wm * 128 + (m + 4) * 16 + lo) * 64 + (((ks * 4 + hi) ^ xr) << 3)];
        if (pre) stgB(buf, t + 2, 1);
        __builtin_amdgcn_sched_barrier(0);
        __builtin_amdgcn_s_barrier();
        __builtin_amdgcn_s_setprio(1);
#pragma unroll
        for (int m = 0; m < 4; ++m)
#pragma unroll
            for (int n = 0; n < 2; ++n)
#pragma unroll
                for (int ks = 0; ks < 2; ++ks)
                    acc[m + 4][n + 2] = __builtin_amdgcn_mfma_f32_16x16x32_bf16(af[m * 2 + ks], b1[n * 2 + ks], acc[m + 4][n + 2], 0, 0, 0);
        __builtin_amdgcn_s_setprio(0);
        __builtin_amdgcn_sched_barrier(0);
        __builtin_amdgcn_s_barrier();
        // ---- g3: stage A-set1{1,3}+B{0,1}(t+2); MFMA Q3; vmcnt(8) -> t+1 landed
        if (pre) { stgA(buf, t + 2, 1); stgB(buf, t + 2, 0); }
        __builtin_amdgcn_sched_barrier(0);
        __builtin_amdgcn_s_setprio(1);
#pragma unroll
        for (int m = 0; m < 4; ++m)
#pragma unroll
            for (int n = 0; n < 2; ++n)
#pragma unroll
                for (int ks = 0; ks < 2; ++ks)
                    acc[m + 4][n] = __builtin_amdgcn_mfma_f32_16x16x32_bf16(af[m * 2 + ks], b0[n * 2 + ks], acc[m + 4][n], 0, 0, 0);
        __builtin_amdgcn_s_setprio(0);
        if (pre) asm volatile("s_waitcnt vmcnt(8)" ::: "memory");
        else     asm volatile("s_waitcnt vmcnt(0)" ::: "memory");
        __builtin_amdgcn_sched_barrier(0);
        __builtin_amdgcn_s_barrier();
    }

#pragma unroll
    for (int m = 0; m < 8; ++m) {
        int row = brow + wm * 128 + m * 16 + hi * 4;
#pragma unroll
        for (int n = 0; n < 4; ++n) {
            float* cp = C + (size_t)row * N + bcol + wn * 64 + n * 16 + lo;
#pragma unroll
            for (int j = 0; j < 4; ++j)
                cp[(size_t)j * N] = acc[m][n][j];
        }
    }
}

// --------- GEMM 256x128, BK=64, out-proj (full machine) --------------------
// 8 waves (4Mx2N), per-wave 64x64. A slots mix g0/g2-read rows -> stage all
// A at g3 (after g2); B fully read by g1-end -> stage both B slots at g2.
__global__ __launch_bounds__(512, 2)
void gemm_bt8n(const __bf16* __restrict__ A, const __bf16* __restrict__ B,
               float* __restrict__ C, int M, int N, int K, int nbx) {
    __shared__ __align__(16) __bf16 sA[2][256 * 64];   // 64 KB
    __shared__ __align__(16) __bf16 sB[2][128 * 64];   // 32 KB
    const int tid = threadIdx.x;
    const int wave = tid >> 6, lane = tid & 63;
    const int lo = lane & 15, hi = lane >> 4;
    const int wm = wave >> 1, wn = wave & 1;
    const int qq = (int)gridDim.x >> 3;
    const int swz = ((int)blockIdx.x & 7) * qq + ((int)blockIdx.x >> 3);
    const int bx = swz % nbx, by = swz / nbx;
    const int brow = by * 256, bcol = bx * 128;
    const int xr = lo & 7;

    int aoff[4], boff[2];
#pragma unroll
    for (int i = 0; i < 4; ++i) {
        int n = i * 512 + tid, r = n >> 3, s = n & 7;
        aoff[i] = r * K + ((s ^ (r & 7)) << 3);
    }
#pragma unroll
    for (int i = 0; i < 2; ++i) {
        int n = i * 512 + tid, r = n >> 3, s = n & 7;
        boff[i] = r * K + ((s ^ (r & 7)) << 3);
    }
    const __bf16* Ab = A + (size_t)brow * K;
    const __bf16* Bb = B + (size_t)bcol * K;

    auto stgAall = [&](int bsel, int kt) {
        const __bf16* ga = Ab + kt * 64;
#pragma unroll
        for (int i = 0; i < 4; ++i)
            gload_lds16(ga + aoff[i], (char*)&sA[bsel][0] + (i * 512 + wave * 64) * 16);
    };
    auto stgBall = [&](int bsel, int kt) {
        const __bf16* gb = Bb + kt * 64;
#pragma unroll
        for (int i = 0; i < 2; ++i)
            gload_lds16(gb + boff[i], (char*)&sB[bsel][0] + (i * 512 + wave * 64) * 16);
    };

    f32x4 acc[4][4] = {};
    const int nt = K >> 6;

    stgAall(0, 0); stgBall(0, 0);      // 6 loads (tile0)
    stgAall(1, 1); stgBall(1, 1);      // 6 loads (tile1)
    asm volatile("s_waitcnt vmcnt(6)" ::: "memory");   // tile0 landed
    __builtin_amdgcn_s_barrier();

    for (int t = 0; t < nt; ++t) {
        const int buf = t & 1;
        const bool pre = (t + 2 < nt);
        const __bf16* sa = &sA[buf][0];
        const __bf16* sb = &sB[buf][0];
        bf16x8 af[4], b0[4], b1[4];
        // ---- g0: ds_read A m01 + B n01; MFMA Q0
#pragma unroll
        for (int m = 0; m < 2; ++m)
#pragma unroll
            for (int ks = 0; ks < 2; ++ks)
                af[m * 2 + ks] = *(const bf16x8*)&sa[(wm * 64 + m * 16 + lo) * 64 + (((ks * 4 + hi) ^ xr) << 3)];
#pragma unroll
        for (int n = 0; n < 2; ++n)
#pragma unroll
            for (int ks = 0; ks < 2; ++ks)
                b0[n * 2 + ks] = *(const bf16x8*)&sb[(wn * 64 + n * 16 + lo) * 64 + (((ks * 4 + hi) ^ xr) << 3)];
        __builtin_amdgcn_sched_barrier(0);
        __builtin_amdgcn_s_barrier();
        __builtin_amdgcn_s_setprio(1);
#pragma unroll
        for (int m = 0; m < 2; ++m)
#pragma unroll
            for (int n = 0; n < 2; ++n)
#pragma unroll
                for (int ks = 0; ks < 2; ++ks)
                    acc[m][n] = __builtin_amdgcn_mfma_f32_16x16x32_bf16(af[m * 2 + ks], b0[n * 2 + ks], acc[m][n], 0, 0, 0);
        __builtin_amdgcn_s_setprio(0);
        __builtin_amdgcn_sched_barrier(0);
        __builtin_amdgcn_s_barrier();
        // ---- g1: ds_read B n23; MFMA Q1
#pragma unroll
        for (int n = 0; n < 2; ++n)
#pragma unroll
            for (int ks = 0; ks < 2; ++ks)
                b1[n * 2 + ks] = *(const bf16x8*)&sb[(wn * 64 + (n + 2) * 16 + lo) * 64 + (((ks * 4 + hi) ^ xr) << 3)];
        __builtin_amdgcn_sched_barrier(0);
        __builtin_amdgcn_s_barrier();
        __builtin_amdgcn_s_setprio(1);
#pragma unroll
        for (int m = 0; m < 2; ++m)
#pragma unroll
            for (int n = 0; n < 2; ++n)
#pragma unroll
                for (int ks = 0; ks < 2; ++ks)
                    acc[m][n + 2] = __builtin_amdgcn_mfma_f32_16x16x32_bf16(af[m * 2 + ks], b1[n * 2 + ks], acc[m][n + 2], 0, 0, 0);
        __builtin_amdgcn_s_setprio(0);
        __builtin_amdgcn_sched_barrier(0);
        __builtin_amdgcn_s_barrier();
        // ---- g2: ds_read A m23; stage B(t+2) (B fully read by g1-end); MFMA Q2
#pragma unroll
        for (int m = 0; m < 2; ++m)
#pragma unroll
            for (int ks = 0; ks < 2; ++ks)
                af[m * 2 + ks] = *(const bf16x8*)&sa[(wm * 64 + (m + 2) * 16 + lo) * 64 + (((ks * 4 + hi) ^ xr) << 3)];
        if (pre) stgBall(buf, t + 2);
        __builtin_amdgcn_sched_barrier(0);
        __builtin_amdgcn_s_barrier();
        __builtin_amdgcn_s_setprio(1);
#pragma unroll
        for (int m = 0; m < 2; ++m)
#pragma unroll
            for (int n = 0; n < 2; ++n)
#pragma unroll
                for (int ks = 0; ks < 2; ++ks)
                    acc[m + 2][n + 2] = __builtin_amdgcn_mfma_f32_16x16x32_bf16(af[m * 2 + ks], b1[n * 2 + ks], acc[m + 2][n + 2], 0, 0, 0);
        __builtin_amdgcn_s_setprio(0);
        __builtin_amdgcn_sched_barrier(0);
        __builtin_amdgcn_s_barrier();
        // ---- g3: stage A(t+2) (A fully read by g2-end); MFMA Q3; vmcnt(6)
        if (pre) stgAall(buf, t + 2);
        __builtin_amdgcn_sched_barrier(0);
        __builtin_amdgcn_s_setprio(1);
#pragma unroll
        for (int m = 0; m < 2; ++m)
#pragma unroll
            for (int n = 0; n < 2; ++n)
#pragma unroll
                for (int ks = 0; ks < 2; ++ks)
                    acc[m + 2][n] = __builtin_amdgcn_mfma_f32_16x16x32_bf16(af[m * 2 + ks], b0[n * 2 + ks], acc[m + 2][n], 0, 0, 0);
        __builtin_amdgcn_s_setprio(0);
        if (pre) asm volatile("s_waitcnt vmcnt(6)" ::: "memory");
        else     asm volatile("s_waitcnt vmcnt(0)" ::: "memory");
        __builtin_amdgcn_sched_barrier(0);
        __builtin_amdgcn_s_barrier();
    }

#pragma unroll
    for (int m = 0; m < 4; ++m) {
        int row = brow + wm * 64 + m * 16 + hi * 4;
#pragma unroll
        for (int n = 0; n < 4; ++n) {
            float* cp = C + (size_t)row * N + bcol + wn * 64 + n * 16 + lo;
#pragma unroll
            for (int j = 0; j < 4; ++j)
                cp[(size_t)j * N] = acc[m][n][j];
        }
    }
}

// ---------- RMSNorm + RoPE (q,k) + V convert, all from QKV f32 -------------
__global__ __launch_bounds__(256)
void norm_rope(const float* __restrict__ QKV, const float* __restrict__ qw,
               const float* __restrict__ kw, const float* __restrict__ cosT,
               const float* __restrict__ sinT, __bf16* __restrict__ Qo,
               __bf16* __restrict__ Ko, __bf16* __restrict__ Vo) {
    const int r = blockIdx.x;            // b*S + s
    const int b = r >> 11, s = r & (SEQ - 1);
    const int wave = threadIdx.x >> 6, lane = threadIdx.x & 63;
    f32x4 cos4 = *(const f32x4*)&cosT[s * 128 + (lane & 31) * 4];
    f32x4 sin4 = *(const f32x4*)&sinT[s * 128 + (lane & 31) * 4];
#pragma unroll
    for (int ii = 0; ii < 4; ++ii) {
        int hh = wave + ii * 4;          // 0..15
        if (hh < 12) {
            bool isq = hh < 8;
            int col0 = isq ? hh * DHEAD : DMODEL + (hh - 8) * DHEAD;
            const float* src = QKV + (size_t)r * 4096 + col0;
            f32x4 x = *(const f32x4*)&src[lane * 4];
            float ss = x[0] * x[0] + x[1] * x[1] + x[2] * x[2] + x[3] * x[3];
#pragma unroll
            for (int d2 = 1; d2 < 64; d2 <<= 1) ss += __shfl_xor(ss, d2);
            float scale = rsqrtf(ss * (1.f / DHEAD) + 1e-6f);
            const float* wp = isq ? qw : kw;
            float nx[4];
#pragma unroll
            for (int j = 0; j < 4; ++j)
                nx[j] = x[j] * scale * (1.f + wp[lane * 4 + j]);
            bf16x4 ov;
#pragma unroll
            for (int j = 0; j < 4; ++j) {
                float other = __shfl_xor(nx[j], 32);
                float rot = (lane < 32) ? -other : other;
                float v = nx[j] * cos4[j] + rot * sin4[j];
                if (isq) v *= 0.0625f;   // SCALE folded into q
                ov[j] = (__bf16)v;
            }
            __bf16* dst = isq ? (Qo + ((size_t)(b * NH + hh) * SEQ + s) * DHEAD)
                              : (Ko + ((size_t)(b * NKV + (hh - 8)) * SEQ + s) * DHEAD);
            *(bf16x4*)&dst[lane * 4] = ov;
        } else {
            int vh = hh - 12;
            const float* src = QKV + (size_t)r * 4096 + 3072 + vh * DHEAD;
            f32x4 x = *(const f32x4*)&src[lane * 4];
            bf16x4 ov;
#pragma unroll
            for (int j = 0; j < 4; ++j) ov[j] = (__bf16)x[j];
            __bf16* dst = Vo + ((size_t)(b * NKV + vh) * SEQ + s) * DHEAD;
            *(bf16x4*)&dst[lane * 4] = ov;
        }
    }
}

// ------------------ flash attention v5 (frozen from round 6) ---------------
__global__ __launch_bounds__(256)
void attn5(const __bf16* __restrict__ Q, const __bf16* __restrict__ Kb,
           const __bf16* __restrict__ Vb, __bf16* __restrict__ ctx) {
    const int bid = blockIdx.x;
    const int bk = bid & 7;            // XCD grouping: same (b,kh) -> same XCD
    const int qt = 63 - (bid >> 3);    // heavy blocks dispatch first
    const int b = bk >> 2, kh = bk & 3;
    const int q0 = qt * 32;
    const int tid = threadIdx.x;
    const int wave = tid >> 6, lane = tid & 63;
    const int lo = lane & 15, hi = lane >> 4;
    const int hsel = wave >> 1, qsub = wave & 1;
    const int h = kh * 2 + hsel;
    const int qbase = q0 + qsub * 16;
    const int q = qbase + lo;

    __shared__ __align__(16) __bf16 kbuf[2][32 * 256];   // 2 x 16 KB
    __shared__ __align__(16) __bf16 vbuf[32 * 256];      // 16 KB single

    const __bf16* Qp = Q + ((size_t)(b * NH + h) * SEQ + qbase) * DHEAD;
    const __bf16* Kp = Kb + (size_t)(b * NKV + kh) * SEQ * DHEAD;
    const __bf16* Vp = Vb + (size_t)(b * NKV + kh) * SEQ * DHEAD;

    int koff[4], voff[4];
#pragma unroll
    for (int i = 0; i < 4; ++i) {
        int n = i * 256 + tid;                 // 16B slot index
        int r = n >> 5, c = n & 31;
        koff[i] = r * 256 + ((c ^ (r & 7)) << 3);
        int st = n >> 3, w = n & 7;
        int vk = (st & 7) * 4 + (w >> 1);
        int vd = (st >> 3) * 16 + (w & 1) * 8;
        voff[i] = vk * 256 + vd;
    }

    auto stageK = [&](int bsel, int c0) {
        const __bf16* kg = Kp + (size_t)c0 * DHEAD;
        char* kd = (char*)&kbuf[bsel][0] + wave * 1024;
#pragma unroll
        for (int i = 0; i < 4; ++i) gload_lds16(kg + koff[i], kd + i * 4096);
    };
    auto stageV = [&](int c0) {
        const __bf16* vg = Vp + (size_t)c0 * DHEAD;
        char* vd = (char*)&vbuf[0] + wave * 1024;
#pragma unroll
        for (int i = 0; i < 4; ++i) gload_lds16(vg + voff[i], vd + i * 4096);
    };

    bf16x8 qf[8];
#pragma unroll
    for (int dc = 0; dc < 8; ++dc)
        qf[dc] = *(const bf16x8*)(Qp + (size_t)lo * DHEAD + dc * 32 + hi * 8);

    f32x4 o[16] = {};
    float m = -3e38f, l = 0.f;

    int kstart = q0 - SWIN; if (kstart < 0) kstart = 0;
    const int nt = (q0 + 32 - kstart) >> 5;

    stageK(0, kstart);
    __syncthreads();                     // K(0) resident (full drain)
    int buf = 0;
    for (int t = 0; t < nt; ++t) {
        const int c0 = kstart + t * 32;
        stageV(c0);                      // vbuf has no readers (post-barrier)
        if (t + 1 < nt) stageK(buf ^ 1, c0 + 32);

        // ---- QK^T (swapped): keys c0+hi*4+j (sc0) / +16 (sc1), q = lo
        f32x4 sc0 = {}, sc1 = {};
        const __bf16* kb0 = &kbuf[buf][0];
        __builtin_amdgcn_s_setprio(1);
#pragma unroll
        for (int dc = 0; dc < 8; ++dc) {
            int u = dc * 4 + hi;
            bf16x8 kfa = *(const bf16x8*)&kb0[lo * 256 + ((u ^ (lo & 7)) << 3)];
            bf16x8 kfb = *(const bf16x8*)&kb0[(16 + lo) * 256 + ((u ^ ((16 + lo) & 7)) << 3)];
            sc0 = __builtin_amdgcn_mfma_f32_16x16x32_bf16(kfa, qf[dc], sc0, 0, 0, 0);
            sc1 = __builtin_amdgcn_mfma_f32_16x16x32_bf16(kfb, qf[dc], sc1, 0, 0, 0);
        }
        __builtin_amdgcn_s_setprio(0);

        // ---- mask + lane-parallel online softmax (state keyed q = lo)
        float s8[8];
#pragma unroll
        for (int j = 0; j < 4; ++j) {
            int ka = c0 + hi * 4 + j;
            int kb2 = ka + 16;
            s8[j]     = (ka <= q && q - ka < SWIN) ? sc0[j] : -1e30f;
            s8[4 + j] = (kb2 <= q && q - kb2 < SWIN) ? sc1[j] : -1e30f;
        }
        float pm = s8[0];
#pragma unroll
        for (int i = 1; i < 8; ++i) pm = fmaxf(pm, s8[i]);
        pm = fmaxf(pm, __shfl_xor(pm, 16));
        pm = fmaxf(pm, __shfl_xor(pm, 32));
        if (__any(pm > m + 8.f)) {             // T13 defer-max
            float mn = fmaxf(m, pm);
            float corr = __expf(m - mn);
            l *= corr;
#pragma unroll
            for (int dt = 0; dt < 16; ++dt) o[dt] *= corr;
            m = mn;
        }
        float p8[8], ps = 0.f;
#pragma unroll
        for (int i = 0; i < 8; ++i) {
            float e = __expf(s8[i] - m);
            p8[i] = (s8[i] > -9e29f) ? e : 0.f;
            ps += p8[i];
        }
        ps += __shfl_xor(ps, 16);
        ps += __shfl_xor(ps, 32);
        l += ps;

        bf16x8 paf;
#pragma unroll
        for (int i = 0; i < 8; ++i) paf[i] = (__bf16)p8[i];

        __syncthreads();                 // V(t) + K(t+1) resident; K reads done

        // ---- PV: o[dt][j] = O^T[d = dt*16+hi*4+j][q = lo]
        const __bf16* vb0 = &vbuf[0];
#pragma unroll
        for (int dq = 0; dq < 4; ++dq) {
            bf16x4 t0[4], t1[4];
#pragma unroll
            for (int u = 0; u < 4; ++u) {
                int dt = dq * 4 + u;
                t0[u] = tr16(vb0 + (dt * 8 + hi) * 64 + lo * 4);       // k-blocks 0..3
                t1[u] = tr16(vb0 + (dt * 8 + 4 + hi) * 64 + lo * 4);   // k-blocks 4..7
            }
            asm volatile("s_waitcnt lgkmcnt(0)" ::: "memory");
            __builtin_amdgcn_sched_barrier(0);
            __builtin_amdgcn_s_setprio(1);
#pragma unroll
            for (int u = 0; u < 4; ++u) {
                bf16x8 vf;
#pragma unroll
                for (int j = 0; j < 4; ++j) { vf[j] = t0[u][j]; vf[4 + j] = t1[u][j]; }
                o[dq * 4 + u] = __builtin_amdgcn_mfma_f32_16x16x32_bf16(vf, paf, o[dq * 4 + u], 0, 0, 0);
            }
            __builtin_amdgcn_s_setprio(0);
        }
        __syncthreads();                 // PV reads retired -> next stageV safe
        buf ^= 1;
    }

    const float invl = 1.0f / l;
    __bf16* cp = ctx + ((size_t)(b * SEQ + q)) * (NH * DHEAD) + h * DHEAD;
#pragma unroll
    for (int dt = 0; dt < 16; ++dt) {
        bf16x4 w;
#pragma unroll
        for (int j = 0; j < 4; ++j) w[j] = (__bf16)(o[dt][j] * invl);
        *(bf16x4*)&cp[dt * 16 + hi * 4] = w;
    }
}

// ---------------------------------------------------------------------------
extern "C" void kernel_launch(void* const* d_in, const int* in_sizes, int n_in,
                              void* d_out, int out_size, void* d_ws, size_t ws_size,
                              hipStream_t stream) {
    const float* hs = (const float*)d_in[0];
    const float* Wq = (const float*)d_in[1];
    const float* Wk = (const float*)d_in[2];
    const float* Wv = (const float*)d_in[3];
    const float* Wo = (const float*)d_in[4];
    const float* qw = (const float*)d_in[5];
    const float* kw = (const float*)d_in[6];
    float* out = (float*)d_out;

    char* ws = (char*)d_ws;
    size_t off = 0;
    auto alloc = [&](size_t bytes) {
        char* p = ws + off;
        off += (bytes + 255) & ~(size_t)255;
        return p;
    };
    const int M = NB * SEQ;                       // 4096
    __bf16* hsB   = (__bf16*)alloc((size_t)M * DMODEL * 2);
    __bf16* WqkvB = (__bf16*)alloc((size_t)4096 * DMODEL * 2);
    __bf16* WoB   = (__bf16*)alloc((size_t)DMODEL * DMODEL * 2);
    float*  QKV   = (float*) alloc((size_t)M * 4096 * 4);
    __bf16* Qb    = (__bf16*)alloc((size_t)M * 2048 * 2);
    __bf16* Kbf   = (__bf16*)alloc((size_t)M * 1024 * 2);
    __bf16* Vbf   = (__bf16*)alloc((size_t)M * 1024 * 2);
    float*  cosT  = (float*) alloc((size_t)SEQ * 128 * 4);
    float*  sinT  = (float*) alloc((size_t)SEQ * 128 * 4);
    __bf16* ctxB  = (__bf16*)QKV;                 // reuse: QKV dead after norm_rope

    rope_tab<<<SEQ, 128, 0, stream>>>(cosT, sinT);
    cvt_all<<<20480, 256, 0, stream>>>(hs, Wq, Wk, Wv, Wo,
                                       hsB, WqkvB, WqkvB + (size_t)2048 * 2048,
                                       WqkvB + (size_t)3072 * 2048, WoB);

    // fused QKV projection: 256 blocks (16x16 tiles of 256)
    gemm_bt8<<<256, 512, 0, stream>>>(hsB, WqkvB, QKV, M, 4096, DMODEL, 16);

    norm_rope<<<M, 256, 0, stream>>>(QKV, qw, kw, cosT, sinT, Qb, Kbf, Vbf);

    attn5<<<512, 256, 0, stream>>>(Qb, Kbf, Vbf, ctxB);

    // output projection: 256 blocks (16x16 tiles of 256x128)
    gemm_bt8n<<<256, 512, 0, stream>>>(ctxB, WoB, out, M, DMODEL, DMODEL, 16);
}

// Round 9
// 216.532 us; speedup vs baseline: 2.0865x; 1.0016x over previous
//
#include <hip/hip_runtime.h>
#include <hip/hip_bf16.h>

// ---------------------------------------------------------------------------
// Gemma sliding-window attention layer, MI355X round 9.
// attn6 = r6's attn5 + counted vmcnt / raw s_barrier (no full drains in the
// main loop), sched_barrier(0) pins on BOTH sides of every s_barrier.
// No permlane (r5 suspect #1), no rolling lgkmcnt. GEMMs/norm/cvt frozen (r8).
// ---------------------------------------------------------------------------

typedef __bf16 bf16x8 __attribute__((ext_vector_type(8)));
typedef __bf16 bf16x4 __attribute__((ext_vector_type(4)));
typedef float f32x4 __attribute__((ext_vector_type(4)));

#define NB 2
#define SEQ 2048
#define DMODEL 2048
#define NH 8
#define NKV 4
#define DHEAD 256
#define SWIN 1024

#define AS1 __attribute__((address_space(1)))
#define AS3 __attribute__((address_space(3)))

static __device__ __forceinline__ void gload_lds16(const void* g, void* l) {
    __builtin_amdgcn_global_load_lds((const AS1 void*)g, (AS3 void*)l, 16, 0, 0);
}

static __device__ __forceinline__ bf16x4 tr16(const __bf16* p) {
    bf16x4 r;
    asm volatile("ds_read_b64_tr_b16 %0, %1" : "=v"(r) : "v"((const AS3 __bf16*)p));
    return r;
}

// ------------------------- merged f32 -> bf16 convert -----------------------
__global__ void cvt_all(const float* __restrict__ s0, const float* __restrict__ s1,
                        const float* __restrict__ s2, const float* __restrict__ s3,
                        const float* __restrict__ s4, __bf16* __restrict__ d0,
                        __bf16* __restrict__ d1, __bf16* __restrict__ d2,
                        __bf16* __restrict__ d3, __bf16* __restrict__ d4) {
    int i = blockIdx.x * 256 + threadIdx.x;      // grid covers exactly 5242880
    const float* src; __bf16* dst;
    if (i < 2097152) { src = s0; dst = d0; }
    else if (i < 3145728) { i -= 2097152; src = s1; dst = d1; }
    else if (i < 3670016) { i -= 3145728; src = s2; dst = d2; }
    else if (i < 4194304) { i -= 3670016; src = s3; dst = d3; }
    else                  { i -= 4194304; src = s4; dst = d4; }
    f32x4 v = ((const f32x4*)src)[i];
    bf16x4 o;
#pragma unroll
    for (int j = 0; j < 4; ++j) o[j] = (__bf16)v[j];
    ((bf16x4*)dst)[i] = o;
}

// ------------------------- RoPE cos/sin table -------------------------------
__global__ void rope_tab(float* __restrict__ cosT, float* __restrict__ sinT) {
    int s = blockIdx.x, i = threadIdx.x;           // i in 0..127
    float fr = (float)s * __expf(-(float)i * 0.0719557843f);  // ln(1e4)/128
    cosT[s * 128 + i] = cosf(fr);
    sinT[s * 128 + i] = sinf(fr);
}

// --------- GEMM 256x256, BK=64, 8-phase pipelined: C = A[M,K] * B[N,K]^T ---
__global__ __launch_bounds__(512, 2)
void gemm_bt8(const __bf16* __restrict__ A, const __bf16* __restrict__ B,
              float* __restrict__ C, int M, int N, int K, int nbx) {
    __shared__ __align__(16) __bf16 sA[2][256 * 64];   // 64 KB
    __shared__ __align__(16) __bf16 sB[2][256 * 64];   // 64 KB
    const int tid = threadIdx.x;
    const int wave = tid >> 6, lane = tid & 63;
    const int lo = lane & 15, hi = lane >> 4;
    const int wm = wave >> 2, wn = wave & 3;
    const int qq = (int)gridDim.x >> 3;
    const int swz = ((int)blockIdx.x & 7) * qq + ((int)blockIdx.x >> 3);
    const int bx = swz % nbx, by = swz / nbx;
    const int brow = by * 256, bcol = bx * 256;
    const int xr = lo & 7;

    int aoff[4];
#pragma unroll
    for (int i = 0; i < 4; ++i) {
        int n = i * 512 + tid, r = n >> 3, s = n & 7;
        aoff[i] = r * K + ((s ^ (r & 7)) << 3);   // pre-swizzled global source
    }
    const __bf16* Ab = A + (size_t)brow * K;
    const __bf16* Bb = B + (size_t)bcol * K;

    auto stgA = [&](int bsel, int kt, int h) {
        const __bf16* ga = Ab + kt * 64;
#pragma unroll
        for (int ii = 0; ii < 2; ++ii) {
            int i = h + ii * 2;
            gload_lds16(ga + aoff[i], (char*)&sA[bsel][0] + (i * 512 + wave * 64) * 16);
        }
    };
    auto stgB = [&](int bsel, int kt, int h) {
        const __bf16* gb = Bb + kt * 64;
#pragma unroll
        for (int i = 2 * h; i < 2 * h + 2; ++i)
            gload_lds16(gb + aoff[i], (char*)&sB[bsel][0] + (i * 512 + wave * 64) * 16);
    };

    f32x4 acc[8][4] = {};
    const int nt = K >> 6;

    stgA(0, 0, 0); stgA(0, 0, 1); stgB(0, 0, 0); stgB(0, 0, 1);
    stgA(1, 1, 0); stgA(1, 1, 1); stgB(1, 1, 0); stgB(1, 1, 1);
    asm volatile("s_waitcnt vmcnt(8)" ::: "memory");   // tile0 landed
    __builtin_amdgcn_s_barrier();

    for (int t = 0; t < nt; ++t) {
        const int buf = t & 1;
        const bool pre = (t + 2 < nt);
        const __bf16* sa = &sA[buf][0];
        const __bf16* sb = &sB[buf][0];
        bf16x8 af[8], b0[4], b1[4];
        // ---- g0: ds_read A rows wm*128+0..63 (slots {0,2}) + B-nh0; MFMA Q0
#pragma unroll
        for (int m = 0; m < 4; ++m)
#pragma unroll
            for (int ks = 0; ks < 2; ++ks)
                af[m * 2 + ks] = *(const bf16x8*)&sa[(wm * 128 + m * 16 + lo) * 64 + (((ks * 4 + hi) ^ xr) << 3)];
#pragma unroll
        for (int n = 0; n < 2; ++n)
#pragma unroll
            for (int ks = 0; ks < 2; ++ks)
                b0[n * 2 + ks] = *(const bf16x8*)&sb[(wn * 64 + n * 16 + lo) * 64 + (((ks * 4 + hi) ^ xr) << 3)];
        __builtin_amdgcn_sched_barrier(0);
        __builtin_amdgcn_s_barrier();
        __builtin_amdgcn_s_setprio(1);
#pragma unroll
        for (int m = 0; m < 4; ++m)
#pragma unroll
            for (int n = 0; n < 2; ++n)
#pragma unroll
                for (int ks = 0; ks < 2; ++ks)
                    acc[m][n] = __builtin_amdgcn_mfma_f32_16x16x32_bf16(af[m * 2 + ks], b0[n * 2 + ks], acc[m][n], 0, 0, 0);
        __builtin_amdgcn_s_setprio(0);
        __builtin_amdgcn_sched_barrier(0);
        __builtin_amdgcn_s_barrier();
        // ---- g1: ds_read B-nh1; stage A-set0(t+2); MFMA Q1
#pragma unroll
        for (int n = 0; n < 2; ++n)
#pragma unroll
            for (int ks = 0; ks < 2; ++ks)
                b1[n * 2 + ks] = *(const bf16x8*)&sb[(wn * 64 + (n + 2) * 16 + lo) * 64 + (((ks * 4 + hi) ^ xr) << 3)];
        if (pre) stgA(buf, t + 2, 0);
        __builtin_amdgcn_sched_barrier(0);
        __builtin_amdgcn_s_barrier();
        __builtin_amdgcn_s_setprio(1);
#pragma unroll
        for (int m = 0; m < 4; ++m)
#pragma unroll
            for (int n = 0; n < 2; ++n)
#pragma unroll
                for (int ks = 0; ks < 2; ++ks)
                    acc[m][n + 2] = __builtin_amdgcn_mfma_f32_16x16x32_bf16(af[m * 2 + ks], b1[n * 2 + ks], acc[m][n + 2], 0, 0, 0);
        __builtin_amdgcn_s_setprio(0);
        __builtin_amdgcn_sched_barrier(0);
        __builtin_amdgcn_s_barrier();
        // ---- g2: ds_read A rows wm*128+64..127 (slots {1,3}); stage B{2,3}(t+2); MFMA Q2
#pragma unroll
        for (int m = 0; m < 4; ++m)
#pragma unroll
            for (int ks = 0; ks < 2; ++ks)
                af[m * 2 + ks] = *(const bf16x8*)&sa[(wm * 128 + (m + 4) * 16 + lo) * 64 + (((ks * 4 + hi) ^ xr) << 3)];
        if (pre) stgB(buf, t + 2, 1);
        __builtin_amdgcn_sched_barrier(0);
        __builtin_amdgcn_s_barrier();
        __builtin_amdgcn_s_setprio(1);
#pragma unroll
        for (int m = 0; m < 4; ++m)
#pragma unroll
            for (int n = 0; n < 2; ++n)
#pragma unroll
                for (int ks = 0; ks < 2; ++ks)
                    acc[m + 4][n + 2] = __builtin_amdgcn_mfma_f32_16x16x32_bf16(af[m * 2 + ks], b1[n * 2 + ks], acc[m + 4][n + 2], 0, 0, 0);
        __builtin_amdgcn_s_setprio(0);
        __builtin_amdgcn_sched_barrier(0);
        __builtin_amdgcn_s_barrier();
        // ---- g3: stage A-set1{1,3}+B{0,1}(t+2); MFMA Q3; vmcnt(8)
        if (pre) { stgA(buf, t + 2, 1); stgB(buf, t + 2, 0); }
        __builtin_amdgcn_sched_barrier(0);
        __builtin_amdgcn_s_setprio(1);
#pragma unroll
        for (int m = 0; m < 4; ++m)
#pragma unroll
            for (int n = 0; n < 2; ++n)
#pragma unroll
                for (int ks = 0; ks < 2; ++ks)
                    acc[m + 4][n] = __builtin_amdgcn_mfma_f32_16x16x32_bf16(af[m * 2 + ks], b0[n * 2 + ks], acc[m + 4][n], 0, 0, 0);
        __builtin_amdgcn_s_setprio(0);
        if (pre) asm volatile("s_waitcnt vmcnt(8)" ::: "memory");
        else     asm volatile("s_waitcnt vmcnt(0)" ::: "memory");
        __builtin_amdgcn_sched_barrier(0);
        __builtin_amdgcn_s_barrier();
    }

#pragma unroll
    for (int m = 0; m < 8; ++m) {
        int row = brow + wm * 128 + m * 16 + hi * 4;
#pragma unroll
        for (int n = 0; n < 4; ++n) {
            float* cp = C + (size_t)row * N + bcol + wn * 64 + n * 16 + lo;
#pragma unroll
            for (int j = 0; j < 4; ++j)
                cp[(size_t)j * N] = acc[m][n][j];
        }
    }
}

// --------- GEMM 256x128, BK=64, out-proj (full machine) --------------------
__global__ __launch_bounds__(512, 2)
void gemm_bt8n(const __bf16* __restrict__ A, const __bf16* __restrict__ B,
               float* __restrict__ C, int M, int N, int K, int nbx) {
    __shared__ __align__(16) __bf16 sA[2][256 * 64];   // 64 KB
    __shared__ __align__(16) __bf16 sB[2][128 * 64];   // 32 KB
    const int tid = threadIdx.x;
    const int wave = tid >> 6, lane = tid & 63;
    const int lo = lane & 15, hi = lane >> 4;
    const int wm = wave >> 1, wn = wave & 1;
    const int qq = (int)gridDim.x >> 3;
    const int swz = ((int)blockIdx.x & 7) * qq + ((int)blockIdx.x >> 3);
    const int bx = swz % nbx, by = swz / nbx;
    const int brow = by * 256, bcol = bx * 128;
    const int xr = lo & 7;

    int aoff[4], boff[2];
#pragma unroll
    for (int i = 0; i < 4; ++i) {
        int n = i * 512 + tid, r = n >> 3, s = n & 7;
        aoff[i] = r * K + ((s ^ (r & 7)) << 3);
    }
#pragma unroll
    for (int i = 0; i < 2; ++i) {
        int n = i * 512 + tid, r = n >> 3, s = n & 7;
        boff[i] = r * K + ((s ^ (r & 7)) << 3);
    }
    const __bf16* Ab = A + (size_t)brow * K;
    const __bf16* Bb = B + (size_t)bcol * K;

    auto stgAall = [&](int bsel, int kt) {
        const __bf16* ga = Ab + kt * 64;
#pragma unroll
        for (int i = 0; i < 4; ++i)
            gload_lds16(ga + aoff[i], (char*)&sA[bsel][0] + (i * 512 + wave * 64) * 16);
    };
    auto stgBall = [&](int bsel, int kt) {
        const __bf16* gb = Bb + kt * 64;
#pragma unroll
        for (int i = 0; i < 2; ++i)
            gload_lds16(gb + boff[i], (char*)&sB[bsel][0] + (i * 512 + wave * 64) * 16);
    };

    f32x4 acc[4][4] = {};
    const int nt = K >> 6;

    stgAall(0, 0); stgBall(0, 0);      // 6 loads (tile0)
    stgAall(1, 1); stgBall(1, 1);      // 6 loads (tile1)
    asm volatile("s_waitcnt vmcnt(6)" ::: "memory");   // tile0 landed
    __builtin_amdgcn_s_barrier();

    for (int t = 0; t < nt; ++t) {
        const int buf = t & 1;
        const bool pre = (t + 2 < nt);
        const __bf16* sa = &sA[buf][0];
        const __bf16* sb = &sB[buf][0];
        bf16x8 af[4], b0[4], b1[4];
        // ---- g0: ds_read A m01 + B n01; MFMA Q0
#pragma unroll
        for (int m = 0; m < 2; ++m)
#pragma unroll
            for (int ks = 0; ks < 2; ++ks)
                af[m * 2 + ks] = *(const bf16x8*)&sa[(wm * 64 + m * 16 + lo) * 64 + (((ks * 4 + hi) ^ xr) << 3)];
#pragma unroll
        for (int n = 0; n < 2; ++n)
#pragma unroll
            for (int ks = 0; ks < 2; ++ks)
                b0[n * 2 + ks] = *(const bf16x8*)&sb[(wn * 64 + n * 16 + lo) * 64 + (((ks * 4 + hi) ^ xr) << 3)];
        __builtin_amdgcn_sched_barrier(0);
        __builtin_amdgcn_s_barrier();
        __builtin_amdgcn_s_setprio(1);
#pragma unroll
        for (int m = 0; m < 2; ++m)
#pragma unroll
            for (int n = 0; n < 2; ++n)
#pragma unroll
                for (int ks = 0; ks < 2; ++ks)
                    acc[m][n] = __builtin_amdgcn_mfma_f32_16x16x32_bf16(af[m * 2 + ks], b0[n * 2 + ks], acc[m][n], 0, 0, 0);
        __builtin_amdgcn_s_setprio(0);
        __builtin_amdgcn_sched_barrier(0);
        __builtin_amdgcn_s_barrier();
        // ---- g1: ds_read B n23; MFMA Q1
#pragma unroll
        for (int n = 0; n < 2; ++n)
#pragma unroll
            for (int ks = 0; ks < 2; ++ks)
                b1[n * 2 + ks] = *(const bf16x8*)&sb[(wn * 64 + (n + 2) * 16 + lo) * 64 + (((ks * 4 + hi) ^ xr) << 3)];
        __builtin_amdgcn_sched_barrier(0);
        __builtin_amdgcn_s_barrier();
        __builtin_amdgcn_s_setprio(1);
#pragma unroll
        for (int m = 0; m < 2; ++m)
#pragma unroll
            for (int n = 0; n < 2; ++n)
#pragma unroll
                for (int ks = 0; ks < 2; ++ks)
                    acc[m][n + 2] = __builtin_amdgcn_mfma_f32_16x16x32_bf16(af[m * 2 + ks], b1[n * 2 + ks], acc[m][n + 2], 0, 0, 0);
        __builtin_amdgcn_s_setprio(0);
        __builtin_amdgcn_sched_barrier(0);
        __builtin_amdgcn_s_barrier();
        // ---- g2: ds_read A m23; stage B(t+2); MFMA Q2
#pragma unroll
        for (int m = 0; m < 2; ++m)
#pragma unroll
            for (int ks = 0; ks < 2; ++ks)
                af[m * 2 + ks] = *(const bf16x8*)&sa[(wm * 64 + (m + 2) * 16 + lo) * 64 + (((ks * 4 + hi) ^ xr) << 3)];
        if (pre) stgBall(buf, t + 2);
        __builtin_amdgcn_sched_barrier(0);
        __builtin_amdgcn_s_barrier();
        __builtin_amdgcn_s_setprio(1);
#pragma unroll
        for (int m = 0; m < 2; ++m)
#pragma unroll
            for (int n = 0; n < 2; ++n)
#pragma unroll
                for (int ks = 0; ks < 2; ++ks)
                    acc[m + 2][n + 2] = __builtin_amdgcn_mfma_f32_16x16x32_bf16(af[m * 2 + ks], b1[n * 2 + ks], acc[m + 2][n + 2], 0, 0, 0);
        __builtin_amdgcn_s_setprio(0);
        __builtin_amdgcn_sched_barrier(0);
        __builtin_amdgcn_s_barrier();
        // ---- g3: stage A(t+2); MFMA Q3; vmcnt(6)
        if (pre) stgAall(buf, t + 2);
        __builtin_amdgcn_sched_barrier(0);
        __builtin_amdgcn_s_setprio(1);
#pragma unroll
        for (int m = 0; m < 2; ++m)
#pragma unroll
            for (int n = 0; n < 2; ++n)
#pragma unroll
                for (int ks = 0; ks < 2; ++ks)
                    acc[m + 2][n] = __builtin_amdgcn_mfma_f32_16x16x32_bf16(af[m * 2 + ks], b0[n * 2 + ks], acc[m + 2][n], 0, 0, 0);
        __builtin_amdgcn_s_setprio(0);
        if (pre) asm volatile("s_waitcnt vmcnt(6)" ::: "memory");
        else     asm volatile("s_waitcnt vmcnt(0)" ::: "memory");
        __builtin_amdgcn_sched_barrier(0);
        __builtin_amdgcn_s_barrier();
    }

#pragma unroll
    for (int m = 0; m < 4; ++m) {
        int row = brow + wm * 64 + m * 16 + hi * 4;
#pragma unroll
        for (int n = 0; n < 4; ++n) {
            float* cp = C + (size_t)row * N + bcol + wn * 64 + n * 16 + lo;
#pragma unroll
            for (int j = 0; j < 4; ++j)
                cp[(size_t)j * N] = acc[m][n][j];
        }
    }
}

// ---------- RMSNorm + RoPE (q,k) + V convert, all from QKV f32 -------------
__global__ __launch_bounds__(256)
void norm_rope(const float* __restrict__ QKV, const float* __restrict__ qw,
               const float* __restrict__ kw, const float* __restrict__ cosT,
               const float* __restrict__ sinT, __bf16* __restrict__ Qo,
               __bf16* __restrict__ Ko, __bf16* __restrict__ Vo) {
    const int r = blockIdx.x;            // b*S + s
    const int b = r >> 11, s = r & (SEQ - 1);
    const int wave = threadIdx.x >> 6, lane = threadIdx.x & 63;
    f32x4 cos4 = *(const f32x4*)&cosT[s * 128 + (lane & 31) * 4];
    f32x4 sin4 = *(const f32x4*)&sinT[s * 128 + (lane & 31) * 4];
#pragma unroll
    for (int ii = 0; ii < 4; ++ii) {
        int hh = wave + ii * 4;          // 0..15
        if (hh < 12) {
            bool isq = hh < 8;
            int col0 = isq ? hh * DHEAD : DMODEL + (hh - 8) * DHEAD;
            const float* src = QKV + (size_t)r * 4096 + col0;
            f32x4 x = *(const f32x4*)&src[lane * 4];
            float ss = x[0] * x[0] + x[1] * x[1] + x[2] * x[2] + x[3] * x[3];
#pragma unroll
            for (int d2 = 1; d2 < 64; d2 <<= 1) ss += __shfl_xor(ss, d2);
            float scale = rsqrtf(ss * (1.f / DHEAD) + 1e-6f);
            const float* wp = isq ? qw : kw;
            float nx[4];
#pragma unroll
            for (int j = 0; j < 4; ++j)
                nx[j] = x[j] * scale * (1.f + wp[lane * 4 + j]);
            bf16x4 ov;
#pragma unroll
            for (int j = 0; j < 4; ++j) {
                float other = __shfl_xor(nx[j], 32);
                float rot = (lane < 32) ? -other : other;
                float v = nx[j] * cos4[j] + rot * sin4[j];
                if (isq) v *= 0.0625f;   // SCALE folded into q
                ov[j] = (__bf16)v;
            }
            __bf16* dst = isq ? (Qo + ((size_t)(b * NH + hh) * SEQ + s) * DHEAD)
                              : (Ko + ((size_t)(b * NKV + (hh - 8)) * SEQ + s) * DHEAD);
            *(bf16x4*)&dst[lane * 4] = ov;
        } else {
            int vh = hh - 12;
            const float* src = QKV + (size_t)r * 4096 + 3072 + vh * DHEAD;
            f32x4 x = *(const f32x4*)&src[lane * 4];
            bf16x4 ov;
#pragma unroll
            for (int j = 0; j < 4; ++j) ov[j] = (__bf16)x[j];
            __bf16* dst = Vo + ((size_t)(b * NKV + vh) * SEQ + s) * DHEAD;
            *(bf16x4*)&dst[lane * 4] = ov;
        }
    }
}

// ------------------ flash attention v6 -------------------------------------
// = attn5 structure with counted vmcnt + raw s_barrier (sched_barrier(0)
// pinned on both sides). Ledger: per tile issue V(t)[4] + K(t+1)[4];
// vmcnt(8) pre-QK^T drains K(t) leftovers (FIFO-oldest); vmcnt(4) pre-PV
// drains V(t); tile-end barrier is raw (WAR only). Boundaries: 4/0.
__global__ __launch_bounds__(256)
void attn6(const __bf16* __restrict__ Q, const __bf16* __restrict__ Kb,
           const __bf16* __restrict__ Vb, __bf16* __restrict__ ctx) {
    const int bid = blockIdx.x;
    const int bk = bid & 7;            // XCD grouping: same (b,kh) -> same XCD
    const int qt = 63 - (bid >> 3);    // heavy blocks dispatch first
    const int b = bk >> 2, kh = bk & 3;
    const int q0 = qt * 32;
    const int tid = threadIdx.x;
    const int wave = tid >> 6, lane = tid & 63;
    const int lo = lane & 15, hi = lane >> 4;
    const int hsel = wave >> 1, qsub = wave & 1;
    const int h = kh * 2 + hsel;
    const int qbase = q0 + qsub * 16;
    const int q = qbase + lo;

    __shared__ __align__(16) __bf16 kbuf[2][32 * 256];   // 2 x 16 KB
    __shared__ __align__(16) __bf16 vbuf[32 * 256];      // 16 KB single

    const __bf16* Qp = Q + ((size_t)(b * NH + h) * SEQ + qbase) * DHEAD;
    const __bf16* Kp = Kb + (size_t)(b * NKV + kh) * SEQ * DHEAD;
    const __bf16* Vp = Vb + (size_t)(b * NKV + kh) * SEQ * DHEAD;

    int koff[4], voff[4];
#pragma unroll
    for (int i = 0; i < 4; ++i) {
        int n = i * 256 + tid;                 // 16B slot index
        int r = n >> 5, c = n & 31;
        koff[i] = r * 256 + ((c ^ (r & 7)) << 3);
        int st = n >> 3, w = n & 7;
        int vk = (st & 7) * 4 + (w >> 1);
        int vd = (st >> 3) * 16 + (w & 1) * 8;
        voff[i] = vk * 256 + vd;
    }

    auto stageK = [&](int bsel, int c0) {
        const __bf16* kg = Kp + (size_t)c0 * DHEAD;
        char* kd = (char*)&kbuf[bsel][0] + wave * 1024;
#pragma unroll
        for (int i = 0; i < 4; ++i) gload_lds16(kg + koff[i], kd + i * 4096);
    };
    auto stageV = [&](int c0) {
        const __bf16* vg = Vp + (size_t)c0 * DHEAD;
        char* vd = (char*)&vbuf[0] + wave * 1024;
#pragma unroll
        for (int i = 0; i < 4; ++i) gload_lds16(vg + voff[i], vd + i * 4096);
    };

    bf16x8 qf[8];
#pragma unroll
    for (int dc = 0; dc < 8; ++dc)
        qf[dc] = *(const bf16x8*)(Qp + (size_t)lo * DHEAD + dc * 32 + hi * 8);

    f32x4 o[16] = {};
    float m = -3e38f, l = 0.f;

    int kstart = q0 - SWIN; if (kstart < 0) kstart = 0;
    const int nt = (q0 + 32 - kstart) >> 5;

    stageK(0, kstart);
    asm volatile("s_waitcnt vmcnt(0)" ::: "memory");   // qf + own K(0): count exact
    int buf = 0;
    for (int t = 0; t < nt; ++t) {
        const int c0 = kstart + t * 32;
        const bool pre = (t + 1 < nt);
        stageV(c0);                          // vbuf has no readers (post end-barrier)
        if (pre) stageK(buf ^ 1, c0 + 32);
        // K(t) resident for all waves: drain to just {V(t), K(t+1)}
        if (pre) asm volatile("s_waitcnt vmcnt(8)" ::: "memory");
        else     asm volatile("s_waitcnt vmcnt(4)" ::: "memory");
        __builtin_amdgcn_sched_barrier(0);
        __builtin_amdgcn_s_barrier();
        __builtin_amdgcn_sched_barrier(0);   // pin QK^T ds_reads below barrier

        // ---- QK^T (swapped): keys c0+hi*4+j (sc0) / +16 (sc1), q = lo
        f32x4 sc0 = {}, sc1 = {};
        const __bf16* kb0 = &kbuf[buf][0];
        __builtin_amdgcn_s_setprio(1);
#pragma unroll
        for (int dc = 0; dc < 8; ++dc) {
            int u = dc * 4 + hi;
            bf16x8 kfa = *(const bf16x8*)&kb0[lo * 256 + ((u ^ (lo & 7)) << 3)];
            bf16x8 kfb = *(const bf16x8*)&kb0[(16 + lo) * 256 + ((u ^ ((16 + lo) & 7)) << 3)];
            sc0 = __builtin_amdgcn_mfma_f32_16x16x32_bf16(kfa, qf[dc], sc0, 0, 0, 0);
            sc1 = __builtin_amdgcn_mfma_f32_16x16x32_bf16(kfb, qf[dc], sc1, 0, 0, 0);
        }
        __builtin_amdgcn_s_setprio(0);

        // ---- mask + lane-parallel online softmax (state keyed q = lo)
        float s8[8];
#pragma unroll
        for (int j = 0; j < 4; ++j) {
            int ka = c0 + hi * 4 + j;
            int kb2 = ka + 16;
            s8[j]     = (ka <= q && q - ka < SWIN) ? sc0[j] : -1e30f;
            s8[4 + j] = (kb2 <= q && q - kb2 < SWIN) ? sc1[j] : -1e30f;
        }
        float pm = s8[0];
#pragma unroll
        for (int i = 1; i < 8; ++i) pm = fmaxf(pm, s8[i]);
        pm = fmaxf(pm, __shfl_xor(pm, 16));
        pm = fmaxf(pm, __shfl_xor(pm, 32));
        if (__any(pm > m + 8.f)) {             // T13 defer-max
            float mn = fmaxf(m, pm);
            float corr = __expf(m - mn);
            l *= corr;
#pragma unroll
            for (int dt = 0; dt < 16; ++dt) o[dt] *= corr;
            m = mn;
        }
        float p8[8], ps = 0.f;
#pragma unroll
        for (int i = 0; i < 8; ++i) {
            float e = __expf(s8[i] - m);
            p8[i] = (s8[i] > -9e29f) ? e : 0.f;
            ps += p8[i];
        }
        ps += __shfl_xor(ps, 16);
        ps += __shfl_xor(ps, 32);
        l += ps;

        bf16x8 paf;
#pragma unroll
        for (int i = 0; i < 8; ++i) paf[i] = (__bf16)p8[i];

        // V(t) resident for all waves: drain to just {K(t+1)}
        if (pre) asm volatile("s_waitcnt vmcnt(4)" ::: "memory");
        else     asm volatile("s_waitcnt vmcnt(0)" ::: "memory");
        __builtin_amdgcn_sched_barrier(0);
        __builtin_amdgcn_s_barrier();
        __builtin_amdgcn_sched_barrier(0);   // pin tr16 reads below barrier

        // ---- PV: o[dt][j] = O^T[d = dt*16+hi*4+j][q = lo]
        const __bf16* vb0 = &vbuf[0];
#pragma unroll
        for (int dq = 0; dq < 4; ++dq) {
            bf16x4 t0[4], t1[4];
#pragma unroll
            for (int u = 0; u < 4; ++u) {
                int dt = dq * 4 + u;
                t0[u] = tr16(vb0 + (dt * 8 + hi) * 64 + lo * 4);       // k-blocks 0..3
                t1[u] = tr16(vb0 + (dt * 8 + 4 + hi) * 64 + lo * 4);   // k-blocks 4..7
            }
            asm volatile("s_waitcnt lgkmcnt(0)" ::: "memory");
            __builtin_amdgcn_sched_barrier(0);
            __builtin_amdgcn_s_setprio(1);
#pragma unroll
            for (int u = 0; u < 4; ++u) {
                bf16x8 vf;
#pragma unroll
                for (int j = 0; j < 4; ++j) { vf[j] = t0[u][j]; vf[4 + j] = t1[u][j]; }
                o[dq * 4 + u] = __builtin_amdgcn_mfma_f32_16x16x32_bf16(vf, paf, o[dq * 4 + u], 0, 0, 0);
            }
            __builtin_amdgcn_s_setprio(0);
        }
        __builtin_amdgcn_sched_barrier(0);
        __builtin_amdgcn_s_barrier();        // raw WAR barrier: PV reads retired
        __builtin_amdgcn_sched_barrier(0);
        buf ^= 1;
    }

    const float invl = 1.0f / l;
    __bf16* cp = ctx + ((size_t)(b * SEQ + q)) * (NH * DHEAD) + h * DHEAD;
#pragma unroll
    for (int dt = 0; dt < 16; ++dt) {
        bf16x4 w;
#pragma unroll
        for (int j = 0; j < 4; ++j) w[j] = (__bf16)(o[dt][j] * invl);
        *(bf16x4*)&cp[dt * 16 + hi * 4] = w;
    }
}

// ---------------------------------------------------------------------------
extern "C" void kernel_launch(void* const* d_in, const int* in_sizes, int n_in,
                              void* d_out, int out_size, void* d_ws, size_t ws_size,
                              hipStream_t stream) {
    const float* hs = (const float*)d_in[0];
    const float* Wq = (const float*)d_in[1];
    const float* Wk = (const float*)d_in[2];
    const float* Wv = (const float*)d_in[3];
    const float* Wo = (const float*)d_in[4];
    const float* qw = (const float*)d_in[5];
    const float* kw = (const float*)d_in[6];
    float* out = (float*)d_out;

    char* ws = (char*)d_ws;
    size_t off = 0;
    auto alloc = [&](size_t bytes) {
        char* p = ws + off;
        off += (bytes + 255) & ~(size_t)255;
        return p;
    };
    const int M = NB * SEQ;                       // 4096
    __bf16* hsB   = (__bf16*)alloc((size_t)M * DMODEL * 2);
    __bf16* WqkvB = (__bf16*)alloc((size_t)4096 * DMODEL * 2);
    __bf16* WoB   = (__bf16*)alloc((size_t)DMODEL * DMODEL * 2);
    float*  QKV   = (float*) alloc((size_t)M * 4096 * 4);
    __bf16* Qb    = (__bf16*)alloc((size_t)M * 2048 * 2);
    __bf16* Kbf   = (__bf16*)alloc((size_t)M * 1024 * 2);
    __bf16* Vbf   = (__bf16*)alloc((size_t)M * 1024 * 2);
    float*  cosT  = (float*) alloc((size_t)SEQ * 128 * 4);
    float*  sinT  = (float*) alloc((size_t)SEQ * 128 * 4);
    __bf16* ctxB  = (__bf16*)QKV;                 // reuse: QKV dead after norm_rope

    rope_tab<<<SEQ, 128, 0, stream>>>(cosT, sinT);
    cvt_all<<<20480, 256, 0, stream>>>(hs, Wq, Wk, Wv, Wo,
                                       hsB, WqkvB, WqkvB + (size_t)2048 * 2048,
                                       WqkvB + (size_t)3072 * 2048, WoB);

    // fused QKV projection: 256 blocks (16x16 tiles of 256)
    gemm_bt8<<<256, 512, 0, stream>>>(hsB, WqkvB, QKV, M, 4096, DMODEL, 16);

    norm_rope<<<M, 256, 0, stream>>>(QKV, qw, kw, cosT, sinT, Qb, Kbf, Vbf);

    attn6<<<512, 256, 0, stream>>>(Qb, Kbf, Vbf, ctxB);

    // output projection: 256 blocks (16x16 tiles of 256x128)
    gemm_bt8n<<<256, 512, 0, stream>>>(ctxB, WoB, out, M, DMODEL, DMODEL, 16);
}

// Round 10
// 205.681 us; speedup vs baseline: 2.1966x; 1.0528x over previous
//
#include <hip/hip_runtime.h>
#include <hip/hip_bf16.h>

// ---------------------------------------------------------------------------
// Gemma sliding-window attention layer, MI355X round 10.
// QKV intermediate now bf16 (gemm_bt8 OUTBF16 epilogue) -> kills 66MB of
// HBM round-trip; norm_rope reads bf16. rope_tab merged into cvt kernel.
// GEMM sync skeleton / attn6 / out-proj frozen from round 9.
// ---------------------------------------------------------------------------

typedef __bf16 bf16x8 __attribute__((ext_vector_type(8)));
typedef __bf16 bf16x4 __attribute__((ext_vector_type(4)));
typedef float f32x4 __attribute__((ext_vector_type(4)));

#define NB 2
#define SEQ 2048
#define DMODEL 2048
#define NH 8
#define NKV 4
#define DHEAD 256
#define SWIN 1024

#define AS1 __attribute__((address_space(1)))
#define AS3 __attribute__((address_space(3)))

static __device__ __forceinline__ void gload_lds16(const void* g, void* l) {
    __builtin_amdgcn_global_load_lds((const AS1 void*)g, (AS3 void*)l, 16, 0, 0);
}

static __device__ __forceinline__ bf16x4 tr16(const __bf16* p) {
    bf16x4 r;
    asm volatile("ds_read_b64_tr_b16 %0, %1" : "=v"(r) : "v"((const AS3 __bf16*)p));
    return r;
}

// ------------------- merged f32->bf16 convert + RoPE table ------------------
// blocks [0,20480): cvt regions (f32x4 units):
//   hs 2097152 | Wq 1048576 | Wk 524288 | Wv 524288 | Wo 1048576
// blocks [20480,21504): rope table, idx in [0, 262144)
__global__ void cvt_rope(const float* __restrict__ s0, const float* __restrict__ s1,
                         const float* __restrict__ s2, const float* __restrict__ s3,
                         const float* __restrict__ s4, __bf16* __restrict__ d0,
                         __bf16* __restrict__ d1, __bf16* __restrict__ d2,
                         __bf16* __restrict__ d3, __bf16* __restrict__ d4,
                         float* __restrict__ cosT, float* __restrict__ sinT) {
    if (blockIdx.x >= 20480) {
        int idx = (blockIdx.x - 20480) * 256 + threadIdx.x;   // < 262144
        int s = idx >> 7, i = idx & 127;
        float fr = (float)s * __expf(-(float)i * 0.0719557843f);  // ln(1e4)/128
        cosT[idx] = cosf(fr);
        sinT[idx] = sinf(fr);
        return;
    }
    int i = blockIdx.x * 256 + threadIdx.x;      // covers exactly 5242880
    const float* src; __bf16* dst;
    if (i < 2097152) { src = s0; dst = d0; }
    else if (i < 3145728) { i -= 2097152; src = s1; dst = d1; }
    else if (i < 3670016) { i -= 3145728; src = s2; dst = d2; }
    else if (i < 4194304) { i -= 3670016; src = s3; dst = d3; }
    else                  { i -= 4194304; src = s4; dst = d4; }
    f32x4 v = ((const f32x4*)src)[i];
    bf16x4 o;
#pragma unroll
    for (int j = 0; j < 4; ++j) o[j] = (__bf16)v[j];
    ((bf16x4*)dst)[i] = o;
}

// --------- GEMM 256x256, BK=64, 8-phase pipelined: C = A[M,K] * B[N,K]^T ---
// OUTBF16: epilogue writes __bf16 C instead of float.
template <int OUTBF16>
__global__ __launch_bounds__(512, 2)
void gemm_bt8(const __bf16* __restrict__ A, const __bf16* __restrict__ B,
              void* __restrict__ Cv, int M, int N, int K, int nbx) {
    __shared__ __align__(16) __bf16 sA[2][256 * 64];   // 64 KB
    __shared__ __align__(16) __bf16 sB[2][256 * 64];   // 64 KB
    const int tid = threadIdx.x;
    const int wave = tid >> 6, lane = tid & 63;
    const int lo = lane & 15, hi = lane >> 4;
    const int wm = wave >> 2, wn = wave & 3;
    const int qq = (int)gridDim.x >> 3;
    const int swz = ((int)blockIdx.x & 7) * qq + ((int)blockIdx.x >> 3);
    const int bx = swz % nbx, by = swz / nbx;
    const int brow = by * 256, bcol = bx * 256;
    const int xr = lo & 7;

    int aoff[4];
#pragma unroll
    for (int i = 0; i < 4; ++i) {
        int n = i * 512 + tid, r = n >> 3, s = n & 7;
        aoff[i] = r * K + ((s ^ (r & 7)) << 3);   // pre-swizzled global source
    }
    const __bf16* Ab = A + (size_t)brow * K;
    const __bf16* Bb = B + (size_t)bcol * K;

    auto stgA = [&](int bsel, int kt, int h) {
        const __bf16* ga = Ab + kt * 64;
#pragma unroll
        for (int ii = 0; ii < 2; ++ii) {
            int i = h + ii * 2;
            gload_lds16(ga + aoff[i], (char*)&sA[bsel][0] + (i * 512 + wave * 64) * 16);
        }
    };
    auto stgB = [&](int bsel, int kt, int h) {
        const __bf16* gb = Bb + kt * 64;
#pragma unroll
        for (int i = 2 * h; i < 2 * h + 2; ++i)
            gload_lds16(gb + aoff[i], (char*)&sB[bsel][0] + (i * 512 + wave * 64) * 16);
    };

    f32x4 acc[8][4] = {};
    const int nt = K >> 6;

    stgA(0, 0, 0); stgA(0, 0, 1); stgB(0, 0, 0); stgB(0, 0, 1);
    stgA(1, 1, 0); stgA(1, 1, 1); stgB(1, 1, 0); stgB(1, 1, 1);
    asm volatile("s_waitcnt vmcnt(8)" ::: "memory");   // tile0 landed
    __builtin_amdgcn_s_barrier();

    for (int t = 0; t < nt; ++t) {
        const int buf = t & 1;
        const bool pre = (t + 2 < nt);
        const __bf16* sa = &sA[buf][0];
        const __bf16* sb = &sB[buf][0];
        bf16x8 af[8], b0[4], b1[4];
        // ---- g0: ds_read A rows wm*128+0..63 (slots {0,2}) + B-nh0; MFMA Q0
#pragma unroll
        for (int m = 0; m < 4; ++m)
#pragma unroll
            for (int ks = 0; ks < 2; ++ks)
                af[m * 2 + ks] = *(const bf16x8*)&sa[(wm * 128 + m * 16 + lo) * 64 + (((ks * 4 + hi) ^ xr) << 3)];
#pragma unroll
        for (int n = 0; n < 2; ++n)
#pragma unroll
            for (int ks = 0; ks < 2; ++ks)
                b0[n * 2 + ks] = *(const bf16x8*)&sb[(wn * 64 + n * 16 + lo) * 64 + (((ks * 4 + hi) ^ xr) << 3)];
        __builtin_amdgcn_sched_barrier(0);
        __builtin_amdgcn_s_barrier();
        __builtin_amdgcn_s_setprio(1);
#pragma unroll
        for (int m = 0; m < 4; ++m)
#pragma unroll
            for (int n = 0; n < 2; ++n)
#pragma unroll
                for (int ks = 0; ks < 2; ++ks)
                    acc[m][n] = __builtin_amdgcn_mfma_f32_16x16x32_bf16(af[m * 2 + ks], b0[n * 2 + ks], acc[m][n], 0, 0, 0);
        __builtin_amdgcn_s_setprio(0);
        __builtin_amdgcn_sched_barrier(0);
        __builtin_amdgcn_s_barrier();
        // ---- g1: ds_read B-nh1; stage A-set0(t+2); MFMA Q1
#pragma unroll
        for (int n = 0; n < 2; ++n)
#pragma unroll
            for (int ks = 0; ks < 2; ++ks)
                b1[n * 2 + ks] = *(const bf16x8*)&sb[(wn * 64 + (n + 2) * 16 + lo) * 64 + (((ks * 4 + hi) ^ xr) << 3)];
        if (pre) stgA(buf, t + 2, 0);
        __builtin_amdgcn_sched_barrier(0);
        __builtin_amdgcn_s_barrier();
        __builtin_amdgcn_s_setprio(1);
#pragma unroll
        for (int m = 0; m < 4; ++m)
#pragma unroll
            for (int n = 0; n < 2; ++n)
#pragma unroll
                for (int ks = 0; ks < 2; ++ks)
                    acc[m][n + 2] = __builtin_amdgcn_mfma_f32_16x16x32_bf16(af[m * 2 + ks], b1[n * 2 + ks], acc[m][n + 2], 0, 0, 0);
        __builtin_amdgcn_s_setprio(0);
        __builtin_amdgcn_sched_barrier(0);
        __builtin_amdgcn_s_barrier();
        // ---- g2: ds_read A rows wm*128+64..127 (slots {1,3}); stage B{2,3}(t+2); MFMA Q2
#pragma unroll
        for (int m = 0; m < 4; ++m)
#pragma unroll
            for (int ks = 0; ks < 2; ++ks)
                af[m * 2 + ks] = *(const bf16x8*)&sa[(wm * 128 + (m + 4) * 16 + lo) * 64 + (((ks * 4 + hi) ^ xr) << 3)];
        if (pre) stgB(buf, t + 2, 1);
        __builtin_amdgcn_sched_barrier(0);
        __builtin_amdgcn_s_barrier();
        __builtin_amdgcn_s_setprio(1);
#pragma unroll
        for (int m = 0; m < 4; ++m)
#pragma unroll
            for (int n = 0; n < 2; ++n)
#pragma unroll
                for (int ks = 0; ks < 2; ++ks)
                    acc[m + 4][n + 2] = __builtin_amdgcn_mfma_f32_16x16x32_bf16(af[m * 2 + ks], b1[n * 2 + ks], acc[m + 4][n + 2], 0, 0, 0);
        __builtin_amdgcn_s_setprio(0);
        __builtin_amdgcn_sched_barrier(0);
        __builtin_amdgcn_s_barrier();
        // ---- g3: stage A-set1{1,3}+B{0,1}(t+2); MFMA Q3; vmcnt(8)
        if (pre) { stgA(buf, t + 2, 1); stgB(buf, t + 2, 0); }
        __builtin_amdgcn_sched_barrier(0);
        __builtin_amdgcn_s_setprio(1);
#pragma unroll
        for (int m = 0; m < 4; ++m)
#pragma unroll
            for (int n = 0; n < 2; ++n)
#pragma unroll
                for (int ks = 0; ks < 2; ++ks)
                    acc[m + 4][n] = __builtin_amdgcn_mfma_f32_16x16x32_bf16(af[m * 2 + ks], b0[n * 2 + ks], acc[m + 4][n], 0, 0, 0);
        __builtin_amdgcn_s_setprio(0);
        if (pre) asm volatile("s_waitcnt vmcnt(8)" ::: "memory");
        else     asm volatile("s_waitcnt vmcnt(0)" ::: "memory");
        __builtin_amdgcn_sched_barrier(0);
        __builtin_amdgcn_s_barrier();
    }

#pragma unroll
    for (int m = 0; m < 8; ++m) {
        int row = brow + wm * 128 + m * 16 + hi * 4;
#pragma unroll
        for (int n = 0; n < 4; ++n) {
            int col = bcol + wn * 64 + n * 16 + lo;
            if constexpr (OUTBF16) {
                __bf16* cp = (__bf16*)Cv + (size_t)row * N + col;
#pragma unroll
                for (int j = 0; j < 4; ++j)
                    cp[(size_t)j * N] = (__bf16)acc[m][n][j];
            } else {
                float* cp = (float*)Cv + (size_t)row * N + col;
#pragma unroll
                for (int j = 0; j < 4; ++j)
                    cp[(size_t)j * N] = acc[m][n][j];
            }
        }
    }
}

// --------- GEMM 256x128, BK=64, out-proj (full machine, frozen) ------------
__global__ __launch_bounds__(512, 2)
void gemm_bt8n(const __bf16* __restrict__ A, const __bf16* __restrict__ B,
               float* __restrict__ C, int M, int N, int K, int nbx) {
    __shared__ __align__(16) __bf16 sA[2][256 * 64];   // 64 KB
    __shared__ __align__(16) __bf16 sB[2][128 * 64];   // 32 KB
    const int tid = threadIdx.x;
    const int wave = tid >> 6, lane = tid & 63;
    const int lo = lane & 15, hi = lane >> 4;
    const int wm = wave >> 1, wn = wave & 1;
    const int qq = (int)gridDim.x >> 3;
    const int swz = ((int)blockIdx.x & 7) * qq + ((int)blockIdx.x >> 3);
    const int bx = swz % nbx, by = swz / nbx;
    const int brow = by * 256, bcol = bx * 128;
    const int xr = lo & 7;

    int aoff[4], boff[2];
#pragma unroll
    for (int i = 0; i < 4; ++i) {
        int n = i * 512 + tid, r = n >> 3, s = n & 7;
        aoff[i] = r * K + ((s ^ (r & 7)) << 3);
    }
#pragma unroll
    for (int i = 0; i < 2; ++i) {
        int n = i * 512 + tid, r = n >> 3, s = n & 7;
        boff[i] = r * K + ((s ^ (r & 7)) << 3);
    }
    const __bf16* Ab = A + (size_t)brow * K;
    const __bf16* Bb = B + (size_t)bcol * K;

    auto stgAall = [&](int bsel, int kt) {
        const __bf16* ga = Ab + kt * 64;
#pragma unroll
        for (int i = 0; i < 4; ++i)
            gload_lds16(ga + aoff[i], (char*)&sA[bsel][0] + (i * 512 + wave * 64) * 16);
    };
    auto stgBall = [&](int bsel, int kt) {
        const __bf16* gb = Bb + kt * 64;
#pragma unroll
        for (int i = 0; i < 2; ++i)
            gload_lds16(gb + boff[i], (char*)&sB[bsel][0] + (i * 512 + wave * 64) * 16);
    };

    f32x4 acc[4][4] = {};
    const int nt = K >> 6;

    stgAall(0, 0); stgBall(0, 0);      // 6 loads (tile0)
    stgAall(1, 1); stgBall(1, 1);      // 6 loads (tile1)
    asm volatile("s_waitcnt vmcnt(6)" ::: "memory");   // tile0 landed
    __builtin_amdgcn_s_barrier();

    for (int t = 0; t < nt; ++t) {
        const int buf = t & 1;
        const bool pre = (t + 2 < nt);
        const __bf16* sa = &sA[buf][0];
        const __bf16* sb = &sB[buf][0];
        bf16x8 af[4], b0[4], b1[4];
        // ---- g0: ds_read A m01 + B n01; MFMA Q0
#pragma unroll
        for (int m = 0; m < 2; ++m)
#pragma unroll
            for (int ks = 0; ks < 2; ++ks)
                af[m * 2 + ks] = *(const bf16x8*)&sa[(wm * 64 + m * 16 + lo) * 64 + (((ks * 4 + hi) ^ xr) << 3)];
#pragma unroll
        for (int n = 0; n < 2; ++n)
#pragma unroll
            for (int ks = 0; ks < 2; ++ks)
                b0[n * 2 + ks] = *(const bf16x8*)&sb[(wn * 64 + n * 16 + lo) * 64 + (((ks * 4 + hi) ^ xr) << 3)];
        __builtin_amdgcn_sched_barrier(0);
        __builtin_amdgcn_s_barrier();
        __builtin_amdgcn_s_setprio(1);
#pragma unroll
        for (int m = 0; m < 2; ++m)
#pragma unroll
            for (int n = 0; n < 2; ++n)
#pragma unroll
                for (int ks = 0; ks < 2; ++ks)
                    acc[m][n] = __builtin_amdgcn_mfma_f32_16x16x32_bf16(af[m * 2 + ks], b0[n * 2 + ks], acc[m][n], 0, 0, 0);
        __builtin_amdgcn_s_setprio(0);
        __builtin_amdgcn_sched_barrier(0);
        __builtin_amdgcn_s_barrier();
        // ---- g1: ds_read B n23; MFMA Q1
#pragma unroll
        for (int n = 0; n < 2; ++n)
#pragma unroll
            for (int ks = 0; ks < 2; ++ks)
                b1[n * 2 + ks] = *(const bf16x8*)&sb[(wn * 64 + (n + 2) * 16 + lo) * 64 + (((ks * 4 + hi) ^ xr) << 3)];
        __builtin_amdgcn_sched_barrier(0);
        __builtin_amdgcn_s_barrier();
        __builtin_amdgcn_s_setprio(1);
#pragma unroll
        for (int m = 0; m < 2; ++m)
#pragma unroll
            for (int n = 0; n < 2; ++n)
#pragma unroll
                for (int ks = 0; ks < 2; ++ks)
                    acc[m][n + 2] = __builtin_amdgcn_mfma_f32_16x16x32_bf16(af[m * 2 + ks], b1[n * 2 + ks], acc[m][n + 2], 0, 0, 0);
        __builtin_amdgcn_s_setprio(0);
        __builtin_amdgcn_sched_barrier(0);
        __builtin_amdgcn_s_barrier();
        // ---- g2: ds_read A m23; stage B(t+2); MFMA Q2
#pragma unroll
        for (int m = 0; m < 2; ++m)
#pragma unroll
            for (int ks = 0; ks < 2; ++ks)
                af[m * 2 + ks] = *(const bf16x8*)&sa[(wm * 64 + (m + 2) * 16 + lo) * 64 + (((ks * 4 + hi) ^ xr) << 3)];
        if (pre) stgBall(buf, t + 2);
        __builtin_amdgcn_sched_barrier(0);
        __builtin_amdgcn_s_barrier();
        __builtin_amdgcn_s_setprio(1);
#pragma unroll
        for (int m = 0; m < 2; ++m)
#pragma unroll
            for (int n = 0; n < 2; ++n)
#pragma unroll
                for (int ks = 0; ks < 2; ++ks)
                    acc[m + 2][n + 2] = __builtin_amdgcn_mfma_f32_16x16x32_bf16(af[m * 2 + ks], b1[n * 2 + ks], acc[m + 2][n + 2], 0, 0, 0);
        __builtin_amdgcn_s_setprio(0);
        __builtin_amdgcn_sched_barrier(0);
        __builtin_amdgcn_s_barrier();
        // ---- g3: stage A(t+2); MFMA Q3; vmcnt(6)
        if (pre) stgAall(buf, t + 2);
        __builtin_amdgcn_sched_barrier(0);
        __builtin_amdgcn_s_setprio(1);
#pragma unroll
        for (int m = 0; m < 2; ++m)
#pragma unroll
            for (int n = 0; n < 2; ++n)
#pragma unroll
                for (int ks = 0; ks < 2; ++ks)
                    acc[m + 2][n] = __builtin_amdgcn_mfma_f32_16x16x32_bf16(af[m * 2 + ks], b0[n * 2 + ks], acc[m + 2][n], 0, 0, 0);
        __builtin_amdgcn_s_setprio(0);
        if (pre) asm volatile("s_waitcnt vmcnt(6)" ::: "memory");
        else     asm volatile("s_waitcnt vmcnt(0)" ::: "memory");
        __builtin_amdgcn_sched_barrier(0);
        __builtin_amdgcn_s_barrier();
    }

#pragma unroll
    for (int m = 0; m < 4; ++m) {
        int row = brow + wm * 64 + m * 16 + hi * 4;
#pragma unroll
        for (int n = 0; n < 4; ++n) {
            float* cp = C + (size_t)row * N + bcol + wn * 64 + n * 16 + lo;
#pragma unroll
            for (int j = 0; j < 4; ++j)
                cp[(size_t)j * N] = acc[m][n][j];
        }
    }
}

// ---------- RMSNorm + RoPE (q,k) + V copy, from QKV bf16 -------------------
__global__ __launch_bounds__(256)
void norm_rope(const __bf16* __restrict__ QKV, const float* __restrict__ qw,
               const float* __restrict__ kw, const float* __restrict__ cosT,
               const float* __restrict__ sinT, __bf16* __restrict__ Qo,
               __bf16* __restrict__ Ko, __bf16* __restrict__ Vo) {
    const int r = blockIdx.x;            // b*S + s
    const int b = r >> 11, s = r & (SEQ - 1);
    const int wave = threadIdx.x >> 6, lane = threadIdx.x & 63;
    f32x4 cos4 = *(const f32x4*)&cosT[s * 128 + (lane & 31) * 4];
    f32x4 sin4 = *(const f32x4*)&sinT[s * 128 + (lane & 31) * 4];
#pragma unroll
    for (int ii = 0; ii < 4; ++ii) {
        int hh = wave + ii * 4;          // 0..15
        if (hh < 12) {
            bool isq = hh < 8;
            int col0 = isq ? hh * DHEAD : DMODEL + (hh - 8) * DHEAD;
            const __bf16* src = QKV + (size_t)r * 4096 + col0;
            bf16x4 xb = *(const bf16x4*)&src[lane * 4];
            float x[4];
#pragma unroll
            for (int j = 0; j < 4; ++j) x[j] = (float)xb[j];
            float ss = x[0] * x[0] + x[1] * x[1] + x[2] * x[2] + x[3] * x[3];
#pragma unroll
            for (int d2 = 1; d2 < 64; d2 <<= 1) ss += __shfl_xor(ss, d2);
            float scale = rsqrtf(ss * (1.f / DHEAD) + 1e-6f);
            const float* wp = isq ? qw : kw;
            float nx[4];
#pragma unroll
            for (int j = 0; j < 4; ++j)
                nx[j] = x[j] * scale * (1.f + wp[lane * 4 + j]);
            bf16x4 ov;
#pragma unroll
            for (int j = 0; j < 4; ++j) {
                float other = __shfl_xor(nx[j], 32);
                float rot = (lane < 32) ? -other : other;
                float v = nx[j] * cos4[j] + rot * sin4[j];
                if (isq) v *= 0.0625f;   // SCALE folded into q
                ov[j] = (__bf16)v;
            }
            __bf16* dst = isq ? (Qo + ((size_t)(b * NH + hh) * SEQ + s) * DHEAD)
                              : (Ko + ((size_t)(b * NKV + (hh - 8)) * SEQ + s) * DHEAD);
            *(bf16x4*)&dst[lane * 4] = ov;
        } else {
            int vh = hh - 12;
            const __bf16* src = QKV + (size_t)r * 4096 + 3072 + vh * DHEAD;
            bf16x4 xb = *(const bf16x4*)&src[lane * 4];
            __bf16* dst = Vo + ((size_t)(b * NKV + vh) * SEQ + s) * DHEAD;
            *(bf16x4*)&dst[lane * 4] = xb;
        }
    }
}

// ------------------ flash attention v6 (frozen from round 9) ---------------
__global__ __launch_bounds__(256)
void attn6(const __bf16* __restrict__ Q, const __bf16* __restrict__ Kb,
           const __bf16* __restrict__ Vb, __bf16* __restrict__ ctx) {
    const int bid = blockIdx.x;
    const int bk = bid & 7;            // XCD grouping: same (b,kh) -> same XCD
    const int qt = 63 - (bid >> 3);    // heavy blocks dispatch first
    const int b = bk >> 2, kh = bk & 3;
    const int q0 = qt * 32;
    const int tid = threadIdx.x;
    const int wave = tid >> 6, lane = tid & 63;
    const int lo = lane & 15, hi = lane >> 4;
    const int hsel = wave >> 1, qsub = wave & 1;
    const int h = kh * 2 + hsel;
    const int qbase = q0 + qsub * 16;
    const int q = qbase + lo;

    __shared__ __align__(16) __bf16 kbuf[2][32 * 256];   // 2 x 16 KB
    __shared__ __align__(16) __bf16 vbuf[32 * 256];      // 16 KB single

    const __bf16* Qp = Q + ((size_t)(b * NH + h) * SEQ + qbase) * DHEAD;
    const __bf16* Kp = Kb + (size_t)(b * NKV + kh) * SEQ * DHEAD;
    const __bf16* Vp = Vb + (size_t)(b * NKV + kh) * SEQ * DHEAD;

    int koff[4], voff[4];
#pragma unroll
    for (int i = 0; i < 4; ++i) {
        int n = i * 256 + tid;                 // 16B slot index
        int r = n >> 5, c = n & 31;
        koff[i] = r * 256 + ((c ^ (r & 7)) << 3);
        int st = n >> 3, w = n & 7;
        int vk = (st & 7) * 4 + (w >> 1);
        int vd = (st >> 3) * 16 + (w & 1) * 8;
        voff[i] = vk * 256 + vd;
    }

    auto stageK = [&](int bsel, int c0) {
        const __bf16* kg = Kp + (size_t)c0 * DHEAD;
        char* kd = (char*)&kbuf[bsel][0] + wave * 1024;
#pragma unroll
        for (int i = 0; i < 4; ++i) gload_lds16(kg + koff[i], kd + i * 4096);
    };
    auto stageV = [&](int c0) {
        const __bf16* vg = Vp + (size_t)c0 * DHEAD;
        char* vd = (char*)&vbuf[0] + wave * 1024;
#pragma unroll
        for (int i = 0; i < 4; ++i) gload_lds16(vg + voff[i], vd + i * 4096);
    };

    bf16x8 qf[8];
#pragma unroll
    for (int dc = 0; dc < 8; ++dc)
        qf[dc] = *(const bf16x8*)(Qp + (size_t)lo * DHEAD + dc * 32 + hi * 8);

    f32x4 o[16] = {};
    float m = -3e38f, l = 0.f;

    int kstart = q0 - SWIN; if (kstart < 0) kstart = 0;
    const int nt = (q0 + 32 - kstart) >> 5;

    stageK(0, kstart);
    asm volatile("s_waitcnt vmcnt(0)" ::: "memory");   // qf + own K(0): count exact
    int buf = 0;
    for (int t = 0; t < nt; ++t) {
        const int c0 = kstart + t * 32;
        const bool pre = (t + 1 < nt);
        stageV(c0);                          // vbuf has no readers (post end-barrier)
        if (pre) stageK(buf ^ 1, c0 + 32);
        // K(t) resident for all waves: drain to just {V(t), K(t+1)}
        if (pre) asm volatile("s_waitcnt vmcnt(8)" ::: "memory");
        else     asm volatile("s_waitcnt vmcnt(4)" ::: "memory");
        __builtin_amdgcn_sched_barrier(0);
        __builtin_amdgcn_s_barrier();
        __builtin_amdgcn_sched_barrier(0);   // pin QK^T ds_reads below barrier

        // ---- QK^T (swapped): keys c0+hi*4+j (sc0) / +16 (sc1), q = lo
        f32x4 sc0 = {}, sc1 = {};
        const __bf16* kb0 = &kbuf[buf][0];
        __builtin_amdgcn_s_setprio(1);
#pragma unroll
        for (int dc = 0; dc < 8; ++dc) {
            int u = dc * 4 + hi;
            bf16x8 kfa = *(const bf16x8*)&kb0[lo * 256 + ((u ^ (lo & 7)) << 3)];
            bf16x8 kfb = *(const bf16x8*)&kb0[(16 + lo) * 256 + ((u ^ ((16 + lo) & 7)) << 3)];
            sc0 = __builtin_amdgcn_mfma_f32_16x16x32_bf16(kfa, qf[dc], sc0, 0, 0, 0);
            sc1 = __builtin_amdgcn_mfma_f32_16x16x32_bf16(kfb, qf[dc], sc1, 0, 0, 0);
        }
        __builtin_amdgcn_s_setprio(0);

        // ---- mask + lane-parallel online softmax (state keyed q = lo)
        float s8[8];
#pragma unroll
        for (int j = 0; j < 4; ++j) {
            int ka = c0 + hi * 4 + j;
            int kb2 = ka + 16;
            s8[j]     = (ka <= q && q - ka < SWIN) ? sc0[j] : -1e30f;
            s8[4 + j] = (kb2 <= q && q - kb2 < SWIN) ? sc1[j] : -1e30f;
        }
        float pm = s8[0];
#pragma unroll
        for (int i = 1; i < 8; ++i) pm = fmaxf(pm, s8[i]);
        pm = fmaxf(pm, __shfl_xor(pm, 16));
        pm = fmaxf(pm, __shfl_xor(pm, 32));
        if (__any(pm > m + 8.f)) {             // T13 defer-max
            float mn = fmaxf(m, pm);
            float corr = __expf(m - mn);
            l *= corr;
#pragma unroll
            for (int dt = 0; dt < 16; ++dt) o[dt] *= corr;
            m = mn;
        }
        float p8[8], ps = 0.f;
#pragma unroll
        for (int i = 0; i < 8; ++i) {
            float e = __expf(s8[i] - m);
            p8[i] = (s8[i] > -9e29f) ? e : 0.f;
            ps += p8[i];
        }
        ps += __shfl_xor(ps, 16);
        ps += __shfl_xor(ps, 32);
        l += ps;

        bf16x8 paf;
#pragma unroll
        for (int i = 0; i < 8; ++i) paf[i] = (__bf16)p8[i];

        // V(t) resident for all waves: drain to just {K(t+1)}
        if (pre) asm volatile("s_waitcnt vmcnt(4)" ::: "memory");
        else     asm volatile("s_waitcnt vmcnt(0)" ::: "memory");
        __builtin_amdgcn_sched_barrier(0);
        __builtin_amdgcn_s_barrier();
        __builtin_amdgcn_sched_barrier(0);   // pin tr16 reads below barrier

        // ---- PV: o[dt][j] = O^T[d = dt*16+hi*4+j][q = lo]
        const __bf16* vb0 = &vbuf[0];
#pragma unroll
        for (int dq = 0; dq < 4; ++dq) {
            bf16x4 t0[4], t1[4];
#pragma unroll
            for (int u = 0; u < 4; ++u) {
                int dt = dq * 4 + u;
                t0[u] = tr16(vb0 + (dt * 8 + hi) * 64 + lo * 4);       // k-blocks 0..3
                t1[u] = tr16(vb0 + (dt * 8 + 4 + hi) * 64 + lo * 4);   // k-blocks 4..7
            }
            asm volatile("s_waitcnt lgkmcnt(0)" ::: "memory");
            __builtin_amdgcn_sched_barrier(0);
            __builtin_amdgcn_s_setprio(1);
#pragma unroll
            for (int u = 0; u < 4; ++u) {
                bf16x8 vf;
#pragma unroll
                for (int j = 0; j < 4; ++j) { vf[j] = t0[u][j]; vf[4 + j] = t1[u][j]; }
                o[dq * 4 + u] = __builtin_amdgcn_mfma_f32_16x16x32_bf16(vf, paf, o[dq * 4 + u], 0, 0, 0);
            }
            __builtin_amdgcn_s_setprio(0);
        }
        __builtin_amdgcn_sched_barrier(0);
        __builtin_amdgcn_s_barrier();        // raw WAR barrier: PV reads retired
        __builtin_amdgcn_sched_barrier(0);
        buf ^= 1;
    }

    const float invl = 1.0f / l;
    __bf16* cp = ctx + ((size_t)(b * SEQ + q)) * (NH * DHEAD) + h * DHEAD;
#pragma unroll
    for (int dt = 0; dt < 16; ++dt) {
        bf16x4 w;
#pragma unroll
        for (int j = 0; j < 4; ++j) w[j] = (__bf16)(o[dt][j] * invl);
        *(bf16x4*)&cp[dt * 16 + hi * 4] = w;
    }
}

// ---------------------------------------------------------------------------
extern "C" void kernel_launch(void* const* d_in, const int* in_sizes, int n_in,
                              void* d_out, int out_size, void* d_ws, size_t ws_size,
                              hipStream_t stream) {
    const float* hs = (const float*)d_in[0];
    const float* Wq = (const float*)d_in[1];
    const float* Wk = (const float*)d_in[2];
    const float* Wv = (const float*)d_in[3];
    const float* Wo = (const float*)d_in[4];
    const float* qw = (const float*)d_in[5];
    const float* kw = (const float*)d_in[6];
    float* out = (float*)d_out;

    char* ws = (char*)d_ws;
    size_t off = 0;
    auto alloc = [&](size_t bytes) {
        char* p = ws + off;
        off += (bytes + 255) & ~(size_t)255;
        return p;
    };
    const int M = NB * SEQ;                       // 4096
    __bf16* hsB   = (__bf16*)alloc((size_t)M * DMODEL * 2);
    __bf16* WqkvB = (__bf16*)alloc((size_t)4096 * DMODEL * 2);
    __bf16* WoB   = (__bf16*)alloc((size_t)DMODEL * DMODEL * 2);
    __bf16* QKVb  = (__bf16*)alloc((size_t)M * 4096 * 2);
    __bf16* Qb    = (__bf16*)alloc((size_t)M * 2048 * 2);
    __bf16* Kbf   = (__bf16*)alloc((size_t)M * 1024 * 2);
    __bf16* Vbf   = (__bf16*)alloc((size_t)M * 1024 * 2);
    float*  cosT  = (float*) alloc((size_t)SEQ * 128 * 4);
    float*  sinT  = (float*) alloc((size_t)SEQ * 128 * 4);
    __bf16* ctxB  = QKVb;                         // reuse: QKV dead after norm_rope

    cvt_rope<<<21504, 256, 0, stream>>>(hs, Wq, Wk, Wv, Wo,
                                        hsB, WqkvB, WqkvB + (size_t)2048 * 2048,
                                        WqkvB + (size_t)3072 * 2048, WoB, cosT, sinT);

    // fused QKV projection: 256 blocks (16x16 tiles of 256), bf16 output
    gemm_bt8<1><<<256, 512, 0, stream>>>(hsB, WqkvB, QKVb, M, 4096, DMODEL, 16);

    norm_rope<<<M, 256, 0, stream>>>(QKVb, qw, kw, cosT, sinT, Qb, Kbf, Vbf);

    attn6<<<512, 256, 0, stream>>>(Qb, Kbf, Vbf, ctxB);

    // output projection: 256 blocks (16x16 tiles of 256x128)
    gemm_bt8n<<<256, 512, 0, stream>>>(ctxB, WoB, out, M, DMODEL, DMODEL, 16);
}